// Round 12
// baseline (249.342 us; speedup 1.0000x reference)
//
#include <hip/hip_runtime.h>
#include <hip/hip_bf16.h>

#define B_TOT 64
#define NB0 8
#define N_TOK 4096
#define D_DIM 128
#define C_REAL 513
#define C_PAD 576
#define NTILE 9   // C_PAD / 64
#define CPB 4     // clusters per segsum block (1 per wave, 4 waves of 256)

typedef __bf16 bf16x8 __attribute__((ext_vector_type(8)));
typedef float f32x4 __attribute__((ext_vector_type(4)));
typedef unsigned short u16x2 __attribute__((ext_vector_type(2)));

static __device__ __forceinline__ unsigned short bf16_bits(float x) {
  __hip_bfloat16 h = __float2bfloat16(x);
  return *reinterpret_cast<unsigned short*>(&h);
}

// ------ kernel 1: per-b0 bincount, weights, shuffle-scan, counting-sort ------
// Scan via per-wave __shfl_up + tiny cross-wave scan: 2 block barriers
// instead of the round-10 Hillis-Steele's 20 (576-thread barriers are slow).
__global__ __launch_bounds__(576) void k_setup(const int* __restrict__ clusters,
                                               float* __restrict__ counts_f,
                                               float* __restrict__ wts,
                                               int* __restrict__ offs_g,
                                               int* __restrict__ sorted) {
  __shared__ int cnt[C_PAD];
  __shared__ int scan[C_PAD];
  __shared__ int rank[C_PAD];
  __shared__ int wsum[9], wpre[9];
  int b0 = blockIdx.x;
  int t = threadIdx.x;
  int lane = t & 63;
  int w = t >> 6;  // 0..8
  cnt[t] = 0;
  rank[t] = 0;
  __syncthreads();
  for (int n = t; n < N_TOK; n += 576)
    atomicAdd(&cnt[clusters[b0 * N_TOK + n]], 1);
  __syncthreads();
  int myc = cnt[t];
  // wave-level inclusive scan
  int v = myc;
#pragma unroll
  for (int off = 1; off < 64; off <<= 1) {
    int u = __shfl_up(v, off, 64);
    if (lane >= off) v += u;
  }
  if (lane == 63) wsum[w] = v;
  __syncthreads();
  if (t < 9) {
    int s = 0;
    for (int i = 0; i < t; ++i) s += wsum[i];
    wpre[t] = s;
  }
  __syncthreads();
  int inc = v + wpre[w];   // inclusive scan over all 576
  scan[t] = inc;
  offs_g[b0 * C_PAD + t] = inc - myc;
  counts_f[b0 * C_PAD + t] = (t < C_REAL) ? (float)myc : 0.0f;
  wts[b0 * C_PAD + t] = (t < C_REAL && myc > 0) ? 1.0f / (float)myc : 0.0f;
  __syncthreads();
  for (int n = t; n < N_TOK; n += 576) {
    int c = clusters[b0 * N_TOK + n];
    int pos = scan[c] - cnt[c] + atomicAdd(&rank[c], 1);
    sorted[b0 * N_TOK + pos] = n;
  }
}

// ------- kernel 2a/2b: per-tensor sorted-gather segmented sums (q,k) ---------
// Split from the fused k_seg (diagnostic + layout): aggregate gather
// transactions identical, so the MSHR-cap model predicts the three per-tensor
// kernels sum to ~139us; each dispatch ~45-55us, letting k_attn/k_gather
// surface in the profile. One cluster per wave, unrolled count in {7,8}.
template <int WEIGHTED>
__global__ __launch_bounds__(256) void k_seg1(const float* __restrict__ src,
                                              const int* __restrict__ sorted,
                                              const int* __restrict__ offs_g,
                                              const float* __restrict__ wts,
                                              __hip_bfloat16* __restrict__ dst) {
  int b = blockIdx.x;
  int b0 = b & (NB0 - 1);
  int c = blockIdx.y * CPB + (threadIdx.x >> 6);
  int lane = threadIdx.x & 63;
  const int* sidx = sorted + (size_t)b0 * N_TOK;
  const float* sb = src + (size_t)b * N_TOK * D_DIM;

  float2 s2 = {0.f, 0.f};
  if (c < C_REAL) {
    int start = offs_g[b0 * C_PAD + c];
    int count = offs_g[b0 * C_PAD + c + 1] - start;
    int l8 = lane & 7;
    int tn = sidx[start + ((l8 < count) ? l8 : 0)];
    float2 xv[8];
#pragma unroll
    for (int j = 0; j < 8; ++j) {
      int n = __shfl(tn, j, 64);
      xv[j] = ((const float2*)(sb + (size_t)n * D_DIM))[lane];
    }
#pragma unroll
    for (int j = 0; j < 8; ++j) {
      bool val = (j < count);
      s2.x += val ? xv[j].x : 0.f;
      s2.y += val ? xv[j].y : 0.f;
    }
    if (WEIGHTED) {
      float w = wts[b0 * C_PAD + c];
      s2.x *= w; s2.y *= w;
    }
  }
  __hip_bfloat162 o;
  o.x = __float2bfloat16(s2.x);
  o.y = __float2bfloat16(s2.y);
  *reinterpret_cast<__hip_bfloat162*>(dst + ((size_t)b * C_PAD + c) * D_DIM + lane * 2) = o;
}

// ------- kernel 2c: v tensor — raw sums, transposed output [b][d][c] ---------
__global__ __launch_bounds__(256) void k_seg_v(const float* __restrict__ v,
                                               const int* __restrict__ sorted,
                                               const int* __restrict__ offs_g,
                                               __hip_bfloat16* __restrict__ v_ct) {
  __shared__ float vbuf[CPB][D_DIM];  // 2 KB
  int b = blockIdx.x;
  int b0 = b & (NB0 - 1);
  int c0 = blockIdx.y * CPB;
  int wave = threadIdx.x >> 6;
  int lane = threadIdx.x & 63;
  int c = c0 + wave;
  const int* sidx = sorted + (size_t)b0 * N_TOK;
  const float* vb = v + (size_t)b * N_TOK * D_DIM;

  float2 vs = {0.f, 0.f};
  if (c < C_REAL) {
    int start = offs_g[b0 * C_PAD + c];
    int count = offs_g[b0 * C_PAD + c + 1] - start;
    int l8 = lane & 7;
    int tn = sidx[start + ((l8 < count) ? l8 : 0)];
    float2 xv[8];
#pragma unroll
    for (int j = 0; j < 8; ++j) {
      int n = __shfl(tn, j, 64);
      xv[j] = ((const float2*)(vb + (size_t)n * D_DIM))[lane];
    }
#pragma unroll
    for (int j = 0; j < 8; ++j) {
      bool val = (j < count);
      vs.x += val ? xv[j].x : 0.f;
      vs.y += val ? xv[j].y : 0.f;
    }
  }
  ((float2*)&vbuf[wave][0])[lane] = vs;
  __syncthreads();
  // transpose-write V: thread t -> dim d = t>>1, 2 clusters per half
  int d = threadIdx.x >> 1;
  int half = threadIdx.x & 1;
  u16x2 o;
#pragma unroll
  for (int j = 0; j < 2; ++j) o[j] = bf16_bits(vbuf[half * 2 + j][d]);
  *reinterpret_cast<u16x2*>(v_ct + ((size_t)b * D_DIM + d) * C_PAD + c0 + half * 2) = o;
}

// ------ kernel 3: fused cluster attention (count-weighted, NO max-shift) -----
// S = Qc Kc^T has std~1.5, |max|<~10 -> exp(S) safely in f32; P=exp(S);
// l=sum(P*counts); O=(P@Vraw)/l. Pad cols: cnt=0 and Vrow=0 -> no contribution.
__global__ __launch_bounds__(256) void k_attn(const __hip_bfloat16* __restrict__ q_cb,
                                              const __hip_bfloat16* __restrict__ k_cb,
                                              const __hip_bfloat16* __restrict__ v_ct,
                                              const float* __restrict__ counts_f,
                                              float* __restrict__ v_out,
                                              float* __restrict__ a0_out) {
  __shared__ __align__(16) __hip_bfloat16 plds[4][16][80];  // P staging per wave
  int b = blockIdx.x;
  int tile = blockIdx.y;
  int wave = threadIdx.x >> 6;
  int lane = threadIdx.x & 63;
  int l15 = lane & 15;
  int lhi = lane >> 4;
  int r0 = tile * 64 + wave * 16;

  const __hip_bfloat16* qb = q_cb + (size_t)b * C_PAD * D_DIM;
  const __hip_bfloat16* kb = k_cb + (size_t)b * C_PAD * D_DIM;
  const __hip_bfloat16* vb = v_ct + (size_t)b * D_DIM * C_PAD;
  const float* cnt = counts_f + (size_t)(b & (NB0 - 1)) * C_PAD;

  bf16x8 afrag[4];
#pragma unroll
  for (int ks = 0; ks < 4; ++ks)
    afrag[ks] = *(const bf16x8*)(qb + (size_t)(r0 + l15) * D_DIM + ks * 32 + lhi * 8);

  float lsum[4], a0v[4];
  f32x4 oacc[8];
#pragma unroll
  for (int r = 0; r < 4; ++r) { lsum[r] = 0.f; a0v[r] = 0.f; }
#pragma unroll
  for (int d = 0; d < 8; ++d) oacc[d] = f32x4{0.f, 0.f, 0.f, 0.f};

  for (int jt = 0; jt < NTILE; ++jt) {
    f32x4 s[4];
#pragma unroll
    for (int js = 0; js < 4; ++js) {
      s[js] = f32x4{0.f, 0.f, 0.f, 0.f};
      const __hip_bfloat16* kr = kb + (size_t)(jt * 64 + js * 16 + l15) * D_DIM + lhi * 8;
#pragma unroll
      for (int ks = 0; ks < 4; ++ks) {
        bf16x8 bfrag = *(const bf16x8*)(kr + ks * 32);
        s[js] = __builtin_amdgcn_mfma_f32_16x16x32_bf16(afrag[ks], bfrag, s[js], 0, 0, 0);
      }
    }
    float csub[4];
#pragma unroll
    for (int js = 0; js < 4; ++js) csub[js] = cnt[jt * 64 + js * 16 + l15];

    float ps[4][4];
#pragma unroll
    for (int r = 0; r < 4; ++r) {
#pragma unroll
      for (int js = 0; js < 4; ++js) {
        float p = __expf(s[js][r]);
        ps[js][r] = p;
        lsum[r] += p * csub[js];   // per-lane partial; reduced once at end
      }
    }
    if (jt == 0 && l15 == 0) {
#pragma unroll
      for (int r = 0; r < 4; ++r) a0v[r] = ps[0][r] * csub[0];
    }
#pragma unroll
    for (int js = 0; js < 4; ++js)
#pragma unroll
      for (int r = 0; r < 4; ++r)
        plds[wave][lhi * 4 + r][js * 16 + l15] = __float2bfloat16(ps[js][r]);
    bf16x8 pfrag[2];
#pragma unroll
    for (int k2 = 0; k2 < 2; ++k2)
      pfrag[k2] = *(const bf16x8*)&plds[wave][l15][k2 * 32 + lhi * 8];
#pragma unroll
    for (int d2 = 0; d2 < 8; ++d2) {
      f32x4 o = oacc[d2];
      const __hip_bfloat16* vr = vb + (size_t)(d2 * 16 + l15) * C_PAD + jt * 64 + lhi * 8;
#pragma unroll
      for (int k2 = 0; k2 < 2; ++k2) {
        bf16x8 vfrag = *(const bf16x8*)(vr + k2 * 32);
        o = __builtin_amdgcn_mfma_f32_16x16x32_bf16(pfrag[k2], vfrag, o, 0, 0, 0);
      }
      oacc[d2] = o;
    }
  }

  // single row-sum reduction (rows live across the 16 lanes sharing lhi)
#pragma unroll
  for (int off = 1; off < 16; off <<= 1) {
#pragma unroll
    for (int r = 0; r < 4; ++r) lsum[r] += __shfl_xor(lsum[r], off, 64);
  }

  float inv[4];
#pragma unroll
  for (int r = 0; r < 4; ++r) inv[r] = 1.f / lsum[r];
  float* vo = v_out + (size_t)b * C_PAD * D_DIM;
#pragma unroll
  for (int r = 0; r < 4; ++r) {
    int row = r0 + lhi * 4 + r;
    if (row < C_REAL) {
#pragma unroll
      for (int d2 = 0; d2 < 8; ++d2)
        vo[(size_t)row * D_DIM + d2 * 16 + l15] = oacc[d2][r] * inv[r];
      if (l15 == 0) a0_out[(size_t)b * C_REAL + row] = a0v[r] * inv[r];
    }
  }
}

// ---------------- kernel 4: broadcast cluster outputs to tokens --------------
__global__ __launch_bounds__(256) void k_gather(const float* __restrict__ v_out,
                                                const int* __restrict__ clusters,
                                                float* __restrict__ out) {
  size_t idx = (size_t)blockIdx.x * 256 + threadIdx.x;
  int quad = (int)(idx & 31);
  size_t row = idx >> 5;
  int b = (int)(row >> 12);
  int n = (int)(row & (N_TOK - 1));
  int c = clusters[(size_t)(b & (NB0 - 1)) * N_TOK + n];
  const float4* src = (const float4*)(v_out + ((size_t)b * C_PAD + c) * D_DIM);
  ((float4*)(out + row * D_DIM))[quad] = src[quad];
}

extern "C" void kernel_launch(void* const* d_in, const int* in_sizes, int n_in,
                              void* d_out, int out_size, void* d_ws, size_t ws_size,
                              hipStream_t stream) {
  const float* q = (const float*)d_in[0];
  const float* k = (const float*)d_in[1];
  const float* v = (const float*)d_in[2];
  const int* clusters = (const int*)d_in[3];
  float* out = (float*)d_out;
  float* a0 = out + (size_t)B_TOT * N_TOK * D_DIM;

  char* ws = (char*)d_ws;
  float* counts_f = (float*)ws;
  float* wts = counts_f + NB0 * C_PAD;
  int* offs_g = (int*)(wts + NB0 * C_PAD);
  int* sorted = offs_g + NB0 * C_PAD;
  __hip_bfloat16* q_cb = (__hip_bfloat16*)(sorted + NB0 * N_TOK);
  size_t cbElems = (size_t)B_TOT * C_PAD * D_DIM;
  __hip_bfloat16* k_cb = q_cb + cbElems;
  __hip_bfloat16* v_ct = k_cb + cbElems;
  float* v_out = (float*)(v_ct + cbElems);

  k_setup<<<NB0, 576, 0, stream>>>(clusters, counts_f, wts, offs_g, sorted);

  dim3 gs(B_TOT, C_PAD / CPB);
  k_seg1<1><<<gs, 256, 0, stream>>>(q, sorted, offs_g, wts, q_cb);
  k_seg1<1><<<gs, 256, 0, stream>>>(k, sorted, offs_g, wts, k_cb);
  k_seg_v<<<gs, 256, 0, stream>>>(v, sorted, offs_g, v_ct);

  k_attn<<<dim3(B_TOT, NTILE), 256, 0, stream>>>(q_cb, k_cb, v_ct, counts_f, v_out, a0);

  k_gather<<<(B_TOT * N_TOK * 32) / 256, 256, 0, stream>>>(v_out, clusters, out);
}

// Round 13
// 234.232 us; speedup vs baseline: 1.0645x; 1.0645x over previous
//
#include <hip/hip_runtime.h>
#include <hip/hip_bf16.h>

#define B_TOT 64
#define NB0 8
#define N_TOK 4096
#define D_DIM 128
#define C_REAL 513
#define C_PAD 576
#define NTILE 9   // C_PAD / 64
#define CPB 4     // clusters per segsum block (1 per wave, 4 waves of 256)
#define RTILES 33 // ceil(C_REAL/16) row-tiles for k_attn

typedef __bf16 bf16x8 __attribute__((ext_vector_type(8)));
typedef float f32x4 __attribute__((ext_vector_type(4)));
typedef unsigned short u16x2 __attribute__((ext_vector_type(2)));

static __device__ __forceinline__ unsigned short bf16_bits(float x) {
  __hip_bfloat16 h = __float2bfloat16(x);
  return *reinterpret_cast<unsigned short*>(&h);
}

// ------ kernel 1: per-b0 bincount, weights, shuffle-scan, counting-sort ------
__global__ __launch_bounds__(576) void k_setup(const int* __restrict__ clusters,
                                               float* __restrict__ counts_f,
                                               float* __restrict__ wts,
                                               int* __restrict__ offs_g,
                                               int* __restrict__ sorted) {
  __shared__ int cnt[C_PAD];
  __shared__ int scan[C_PAD];
  __shared__ int rank[C_PAD];
  __shared__ int wsum[9], wpre[9];
  int b0 = blockIdx.x;
  int t = threadIdx.x;
  int lane = t & 63;
  int w = t >> 6;  // 0..8
  cnt[t] = 0;
  rank[t] = 0;
  __syncthreads();
  for (int n = t; n < N_TOK; n += 576)
    atomicAdd(&cnt[clusters[b0 * N_TOK + n]], 1);
  __syncthreads();
  int myc = cnt[t];
  int v = myc;
#pragma unroll
  for (int off = 1; off < 64; off <<= 1) {
    int u = __shfl_up(v, off, 64);
    if (lane >= off) v += u;
  }
  if (lane == 63) wsum[w] = v;
  __syncthreads();
  if (t < 9) {
    int s = 0;
    for (int i = 0; i < t; ++i) s += wsum[i];
    wpre[t] = s;
  }
  __syncthreads();
  int inc = v + wpre[w];   // inclusive scan over all 576
  scan[t] = inc;
  offs_g[b0 * C_PAD + t] = inc - myc;
  counts_f[b0 * C_PAD + t] = (t < C_REAL) ? (float)myc : 0.0f;
  wts[b0 * C_PAD + t] = (t < C_REAL && myc > 0) ? 1.0f / (float)myc : 0.0f;
  __syncthreads();
  for (int n = t; n < N_TOK; n += 576) {
    int c = clusters[b0 * N_TOK + n];
    int pos = scan[c] - cnt[c] + atomicAdd(&rank[c], 1);
    sorted[b0 * N_TOK + pos] = n;
  }
}

// ------- kernel 2a/2b: per-tensor sorted-gather segmented sums (q,k) ---------
// ~139us aggregate = HW wall for the 402MB permutation gather (rounds 2-9).
template <int WEIGHTED>
__global__ __launch_bounds__(256) void k_seg1(const float* __restrict__ src,
                                              const int* __restrict__ sorted,
                                              const int* __restrict__ offs_g,
                                              const float* __restrict__ wts,
                                              __hip_bfloat16* __restrict__ dst) {
  int b = blockIdx.x;
  int b0 = b & (NB0 - 1);
  int c = blockIdx.y * CPB + (threadIdx.x >> 6);
  int lane = threadIdx.x & 63;
  const int* sidx = sorted + (size_t)b0 * N_TOK;
  const float* sb = src + (size_t)b * N_TOK * D_DIM;

  float2 s2 = {0.f, 0.f};
  if (c < C_REAL) {
    int start = offs_g[b0 * C_PAD + c];
    int count = offs_g[b0 * C_PAD + c + 1] - start;
    int l8 = lane & 7;
    int tn = sidx[start + ((l8 < count) ? l8 : 0)];
    float2 xv[8];
#pragma unroll
    for (int j = 0; j < 8; ++j) {
      int n = __shfl(tn, j, 64);
      xv[j] = ((const float2*)(sb + (size_t)n * D_DIM))[lane];
    }
#pragma unroll
    for (int j = 0; j < 8; ++j) {
      bool val = (j < count);
      s2.x += val ? xv[j].x : 0.f;
      s2.y += val ? xv[j].y : 0.f;
    }
    if (WEIGHTED) {
      float w = wts[b0 * C_PAD + c];
      s2.x *= w; s2.y *= w;
    }
  }
  __hip_bfloat162 o;
  o.x = __float2bfloat16(s2.x);
  o.y = __float2bfloat16(s2.y);
  *reinterpret_cast<__hip_bfloat162*>(dst + ((size_t)b * C_PAD + c) * D_DIM + lane * 2) = o;
}

// ------- kernel 2c: v tensor — raw sums, transposed output [b][d][c] ---------
__global__ __launch_bounds__(256) void k_seg_v(const float* __restrict__ v,
                                               const int* __restrict__ sorted,
                                               const int* __restrict__ offs_g,
                                               __hip_bfloat16* __restrict__ v_ct) {
  __shared__ float vbuf[CPB][D_DIM];  // 2 KB
  int b = blockIdx.x;
  int b0 = b & (NB0 - 1);
  int c0 = blockIdx.y * CPB;
  int wave = threadIdx.x >> 6;
  int lane = threadIdx.x & 63;
  int c = c0 + wave;
  const int* sidx = sorted + (size_t)b0 * N_TOK;
  const float* vb = v + (size_t)b * N_TOK * D_DIM;

  float2 vs = {0.f, 0.f};
  if (c < C_REAL) {
    int start = offs_g[b0 * C_PAD + c];
    int count = offs_g[b0 * C_PAD + c + 1] - start;
    int l8 = lane & 7;
    int tn = sidx[start + ((l8 < count) ? l8 : 0)];
    float2 xv[8];
#pragma unroll
    for (int j = 0; j < 8; ++j) {
      int n = __shfl(tn, j, 64);
      xv[j] = ((const float2*)(vb + (size_t)n * D_DIM))[lane];
    }
#pragma unroll
    for (int j = 0; j < 8; ++j) {
      bool val = (j < count);
      vs.x += val ? xv[j].x : 0.f;
      vs.y += val ? xv[j].y : 0.f;
    }
  }
  ((float2*)&vbuf[wave][0])[lane] = vs;
  __syncthreads();
  int d = threadIdx.x >> 1;
  int half = threadIdx.x & 1;
  u16x2 o;
#pragma unroll
  for (int j = 0; j < 2; ++j) o[j] = bf16_bits(vbuf[half * 2 + j][d]);
  *reinterpret_cast<u16x2*>(v_ct + ((size_t)b * D_DIM + d) * C_PAD + c0 + half * 2) = o;
}

// ------ kernel 3: cluster attention, col-split across waves ------------------
// Round-12 rocprof: old k_attn = 104us, MfmaUtil 3.9%, occ 20% — tiny grid
// (2.25 blocks/CU) x 9-tile serial chain per wave. New shape: block = 16 rows
// (grid 64x33), 4 waves partition the 9 col-tiles (jt = w, w+4, w+8); no-max
// softmax makes lsum/oacc partials additive; pairwise LDS reduction at end.
// 4x waves, 3.6x shorter critical path.
__global__ __launch_bounds__(256) void k_attn(const __hip_bfloat16* __restrict__ q_cb,
                                              const __hip_bfloat16* __restrict__ k_cb,
                                              const __hip_bfloat16* __restrict__ v_ct,
                                              const float* __restrict__ counts_f,
                                              float* __restrict__ v_out,
                                              float* __restrict__ a0_out) {
  __shared__ __align__(16) __hip_bfloat16 plds[4][16][80];  // 10 KB
  __shared__ float redA[64][33];                            // 8.25 KB
  __shared__ float redB[64][33];                            // 8.25 KB
  __shared__ float lsumBuf[4][16];
  int b = blockIdx.x;
  int r0 = blockIdx.y * 16;
  int wave = threadIdx.x >> 6;
  int lane = threadIdx.x & 63;
  int l15 = lane & 15;
  int lhi = lane >> 4;

  const __hip_bfloat16* qb = q_cb + (size_t)b * C_PAD * D_DIM;
  const __hip_bfloat16* kb = k_cb + (size_t)b * C_PAD * D_DIM;
  const __hip_bfloat16* vb = v_ct + (size_t)b * D_DIM * C_PAD;
  const float* cnt = counts_f + (size_t)(b & (NB0 - 1)) * C_PAD;

  bf16x8 afrag[4];
#pragma unroll
  for (int ks = 0; ks < 4; ++ks)
    afrag[ks] = *(const bf16x8*)(qb + (size_t)(r0 + l15) * D_DIM + ks * 32 + lhi * 8);

  float lsum[4] = {0.f, 0.f, 0.f, 0.f};
  float a0v[4] = {0.f, 0.f, 0.f, 0.f};
  f32x4 oacc[8];
#pragma unroll
  for (int d = 0; d < 8; ++d) oacc[d] = f32x4{0.f, 0.f, 0.f, 0.f};

  for (int jt = wave; jt < NTILE; jt += 4) {
    f32x4 s[4];
#pragma unroll
    for (int js = 0; js < 4; ++js) {
      s[js] = f32x4{0.f, 0.f, 0.f, 0.f};
      const __hip_bfloat16* kr = kb + (size_t)(jt * 64 + js * 16 + l15) * D_DIM + lhi * 8;
#pragma unroll
      for (int ks = 0; ks < 4; ++ks) {
        bf16x8 bfrag = *(const bf16x8*)(kr + ks * 32);
        s[js] = __builtin_amdgcn_mfma_f32_16x16x32_bf16(afrag[ks], bfrag, s[js], 0, 0, 0);
      }
    }
    float csub[4];
#pragma unroll
    for (int js = 0; js < 4; ++js) csub[js] = cnt[jt * 64 + js * 16 + l15];

    float ps[4][4];
#pragma unroll
    for (int r = 0; r < 4; ++r) {
#pragma unroll
      for (int js = 0; js < 4; ++js) {
        float p = __expf(s[js][r]);
        ps[js][r] = p;
        lsum[r] += p * csub[js];
      }
    }
    if (jt == 0 && l15 == 0) {          // only wave 0 has jt==0
#pragma unroll
      for (int r = 0; r < 4; ++r) a0v[r] = ps[0][r] * csub[0];
    }
#pragma unroll
    for (int js = 0; js < 4; ++js)
#pragma unroll
      for (int r = 0; r < 4; ++r)
        plds[wave][lhi * 4 + r][js * 16 + l15] = __float2bfloat16(ps[js][r]);
    bf16x8 pfrag[2];
#pragma unroll
    for (int k2 = 0; k2 < 2; ++k2)
      pfrag[k2] = *(const bf16x8*)&plds[wave][l15][k2 * 32 + lhi * 8];
#pragma unroll
    for (int d2 = 0; d2 < 8; ++d2) {
      f32x4 o = oacc[d2];
      const __hip_bfloat16* vr = vb + (size_t)(d2 * 16 + l15) * C_PAD + jt * 64 + lhi * 8;
#pragma unroll
      for (int k2 = 0; k2 < 2; ++k2) {
        bf16x8 vfrag = *(const bf16x8*)(vr + k2 * 32);
        o = __builtin_amdgcn_mfma_f32_16x16x32_bf16(pfrag[k2], vfrag, o, 0, 0, 0);
      }
      oacc[d2] = o;
    }
  }

  // intra-wave row-sum over the 16 lanes sharing lhi
#pragma unroll
  for (int off = 1; off < 16; off <<= 1) {
#pragma unroll
    for (int r = 0; r < 4; ++r) lsum[r] += __shfl_xor(lsum[r], off, 64);
  }
  if (l15 == 0) {
#pragma unroll
    for (int r = 0; r < 4; ++r) lsumBuf[wave][lhi * 4 + r] = lsum[r];
  }
  // pairwise cross-wave oacc reduction: w1->w0, w3->w2, w2->w0
  if (wave == 1 || wave == 3) {
    float (*buf)[33] = (wave == 1) ? redA : redB;
#pragma unroll
    for (int d2 = 0; d2 < 8; ++d2)
#pragma unroll
      for (int r = 0; r < 4; ++r) buf[lane][d2 * 4 + r] = oacc[d2][r];
  }
  __syncthreads();
  if (wave == 0) {
#pragma unroll
    for (int d2 = 0; d2 < 8; ++d2)
#pragma unroll
      for (int r = 0; r < 4; ++r) oacc[d2][r] += redA[lane][d2 * 4 + r];
  }
  if (wave == 2) {
#pragma unroll
    for (int d2 = 0; d2 < 8; ++d2)
#pragma unroll
      for (int r = 0; r < 4; ++r) oacc[d2][r] += redB[lane][d2 * 4 + r];
  }
  __syncthreads();
  if (wave == 2) {
#pragma unroll
    for (int d2 = 0; d2 < 8; ++d2)
#pragma unroll
      for (int r = 0; r < 4; ++r) redA[lane][d2 * 4 + r] = oacc[d2][r];
  }
  __syncthreads();
  if (wave == 0) {
    float inv[4];
#pragma unroll
    for (int r = 0; r < 4; ++r) {
      int rr = lhi * 4 + r;
      float t = lsumBuf[0][rr] + lsumBuf[1][rr] + lsumBuf[2][rr] + lsumBuf[3][rr];
      inv[r] = 1.f / t;
    }
    float* vo = v_out + (size_t)b * C_PAD * D_DIM;
#pragma unroll
    for (int r = 0; r < 4; ++r) {
      int row = r0 + lhi * 4 + r;
      if (row < C_REAL) {
#pragma unroll
        for (int d2 = 0; d2 < 8; ++d2)
          vo[(size_t)row * D_DIM + d2 * 16 + l15] =
              (oacc[d2][r] + redA[lane][d2 * 4 + r]) * inv[r];
        if (l15 == 0) a0_out[(size_t)b * C_REAL + row] = a0v[r] * inv[r];
      }
    }
  }
}

// ---------------- kernel 4: broadcast cluster outputs to tokens --------------
__global__ __launch_bounds__(256) void k_gather(const float* __restrict__ v_out,
                                                const int* __restrict__ clusters,
                                                float* __restrict__ out) {
  size_t idx = (size_t)blockIdx.x * 256 + threadIdx.x;
  int quad = (int)(idx & 31);
  size_t row = idx >> 5;
  int b = (int)(row >> 12);
  int n = (int)(row & (N_TOK - 1));
  int c = clusters[(size_t)(b & (NB0 - 1)) * N_TOK + n];
  const float4* src = (const float4*)(v_out + ((size_t)b * C_PAD + c) * D_DIM);
  ((float4*)(out + row * D_DIM))[quad] = src[quad];
}

extern "C" void kernel_launch(void* const* d_in, const int* in_sizes, int n_in,
                              void* d_out, int out_size, void* d_ws, size_t ws_size,
                              hipStream_t stream) {
  const float* q = (const float*)d_in[0];
  const float* k = (const float*)d_in[1];
  const float* v = (const float*)d_in[2];
  const int* clusters = (const int*)d_in[3];
  float* out = (float*)d_out;
  float* a0 = out + (size_t)B_TOT * N_TOK * D_DIM;

  char* ws = (char*)d_ws;
  float* counts_f = (float*)ws;
  float* wts = counts_f + NB0 * C_PAD;
  int* offs_g = (int*)(wts + NB0 * C_PAD);
  int* sorted = offs_g + NB0 * C_PAD;
  __hip_bfloat16* q_cb = (__hip_bfloat16*)(sorted + NB0 * N_TOK);
  size_t cbElems = (size_t)B_TOT * C_PAD * D_DIM;
  __hip_bfloat16* k_cb = q_cb + cbElems;
  __hip_bfloat16* v_ct = k_cb + cbElems;
  float* v_out = (float*)(v_ct + cbElems);

  k_setup<<<NB0, 576, 0, stream>>>(clusters, counts_f, wts, offs_g, sorted);

  dim3 gs(B_TOT, C_PAD / CPB);
  k_seg1<1><<<gs, 256, 0, stream>>>(q, sorted, offs_g, wts, q_cb);
  k_seg1<1><<<gs, 256, 0, stream>>>(k, sorted, offs_g, wts, k_cb);
  k_seg_v<<<gs, 256, 0, stream>>>(v, sorted, offs_g, v_ct);

  k_attn<<<dim3(B_TOT, RTILES), 256, 0, stream>>>(q_cb, k_cb, v_ct, counts_f, v_out, a0);

  k_gather<<<(B_TOT * N_TOK * 32) / 256, 256, 0, stream>>>(v_out, clusters, out);
}

// Round 14
// 188.753 us; speedup vs baseline: 1.3210x; 1.2409x over previous
//
#include <hip/hip_runtime.h>
#include <hip/hip_bf16.h>

#define B_TOT 64
#define NB0 8
#define N_TOK 4096
#define D_DIM 128
#define C_REAL 513
#define C_PAD 576
#define NTILE 9   // C_PAD / 64
#define CPB 4     // clusters per segsum block (1 per wave, 4 waves of 256)

typedef __bf16 bf16x8 __attribute__((ext_vector_type(8)));
typedef float f32x4 __attribute__((ext_vector_type(4)));
typedef unsigned short u16x2 __attribute__((ext_vector_type(2)));

static __device__ __forceinline__ unsigned short bf16_bits(float x) {
  __hip_bfloat16 h = __float2bfloat16(x);
  return *reinterpret_cast<unsigned short*>(&h);
}

// ------ kernel 1: per-b0 bincount, weights, shuffle-scan, counting-sort ------
__global__ __launch_bounds__(576) void k_setup(const int* __restrict__ clusters,
                                               float* __restrict__ counts_f,
                                               float* __restrict__ wts,
                                               int* __restrict__ offs_g,
                                               int* __restrict__ sorted) {
  __shared__ int cnt[C_PAD];
  __shared__ int scan[C_PAD];
  __shared__ int rank[C_PAD];
  __shared__ int wsum[9], wpre[9];
  int b0 = blockIdx.x;
  int t = threadIdx.x;
  int lane = t & 63;
  int w = t >> 6;  // 0..8
  cnt[t] = 0;
  rank[t] = 0;
  __syncthreads();
  for (int n = t; n < N_TOK; n += 576)
    atomicAdd(&cnt[clusters[b0 * N_TOK + n]], 1);
  __syncthreads();
  int myc = cnt[t];
  int v = myc;
#pragma unroll
  for (int off = 1; off < 64; off <<= 1) {
    int u = __shfl_up(v, off, 64);
    if (lane >= off) v += u;
  }
  if (lane == 63) wsum[w] = v;
  __syncthreads();
  if (t < 9) {
    int s = 0;
    for (int i = 0; i < t; ++i) s += wsum[i];
    wpre[t] = s;
  }
  __syncthreads();
  int inc = v + wpre[w];   // inclusive scan over all 576
  scan[t] = inc;
  offs_g[b0 * C_PAD + t] = inc - myc;
  counts_f[b0 * C_PAD + t] = (t < C_REAL) ? (float)myc : 0.0f;
  wts[b0 * C_PAD + t] = (t < C_REAL && myc > 0) ? 1.0f / (float)myc : 0.0f;
  __syncthreads();
  for (int n = t; n < N_TOK; n += 576) {
    int c = clusters[b0 * N_TOK + n];
    int pos = scan[c] - cnt[c] + atomicAdd(&rank[c], 1);
    sorted[b0 * N_TOK + pos] = n;
  }
}

// ------- kernel 2a/2b: per-tensor sorted-gather segmented sums (q,k) ---------
// ~139us aggregate = HW wall for the 402MB permutation gather (rounds 2-9).
template <int WEIGHTED>
__global__ __launch_bounds__(256) void k_seg1(const float* __restrict__ src,
                                              const int* __restrict__ sorted,
                                              const int* __restrict__ offs_g,
                                              const float* __restrict__ wts,
                                              __hip_bfloat16* __restrict__ dst) {
  int b = blockIdx.x;
  int b0 = b & (NB0 - 1);
  int c = blockIdx.y * CPB + (threadIdx.x >> 6);
  int lane = threadIdx.x & 63;
  const int* sidx = sorted + (size_t)b0 * N_TOK;
  const float* sb = src + (size_t)b * N_TOK * D_DIM;

  float2 s2 = {0.f, 0.f};
  if (c < C_REAL) {
    int start = offs_g[b0 * C_PAD + c];
    int count = offs_g[b0 * C_PAD + c + 1] - start;
    int l8 = lane & 7;
    int tn = sidx[start + ((l8 < count) ? l8 : 0)];
    float2 xv[8];
#pragma unroll
    for (int j = 0; j < 8; ++j) {
      int n = __shfl(tn, j, 64);
      xv[j] = ((const float2*)(sb + (size_t)n * D_DIM))[lane];
    }
#pragma unroll
    for (int j = 0; j < 8; ++j) {
      bool val = (j < count);
      s2.x += val ? xv[j].x : 0.f;
      s2.y += val ? xv[j].y : 0.f;
    }
    if (WEIGHTED) {
      float w = wts[b0 * C_PAD + c];
      s2.x *= w; s2.y *= w;
    }
  }
  __hip_bfloat162 o;
  o.x = __float2bfloat16(s2.x);
  o.y = __float2bfloat16(s2.y);
  *reinterpret_cast<__hip_bfloat162*>(dst + ((size_t)b * C_PAD + c) * D_DIM + lane * 2) = o;
}

// ------- kernel 2c: v tensor — raw sums, transposed output [b][d][c] ---------
__global__ __launch_bounds__(256) void k_seg_v(const float* __restrict__ v,
                                               const int* __restrict__ sorted,
                                               const int* __restrict__ offs_g,
                                               __hip_bfloat16* __restrict__ v_ct) {
  __shared__ float vbuf[CPB][D_DIM];  // 2 KB
  int b = blockIdx.x;
  int b0 = b & (NB0 - 1);
  int c0 = blockIdx.y * CPB;
  int wave = threadIdx.x >> 6;
  int lane = threadIdx.x & 63;
  int c = c0 + wave;
  const int* sidx = sorted + (size_t)b0 * N_TOK;
  const float* vb = v + (size_t)b * N_TOK * D_DIM;

  float2 vs = {0.f, 0.f};
  if (c < C_REAL) {
    int start = offs_g[b0 * C_PAD + c];
    int count = offs_g[b0 * C_PAD + c + 1] - start;
    int l8 = lane & 7;
    int tn = sidx[start + ((l8 < count) ? l8 : 0)];
    float2 xv[8];
#pragma unroll
    for (int j = 0; j < 8; ++j) {
      int n = __shfl(tn, j, 64);
      xv[j] = ((const float2*)(vb + (size_t)n * D_DIM))[lane];
    }
#pragma unroll
    for (int j = 0; j < 8; ++j) {
      bool val = (j < count);
      vs.x += val ? xv[j].x : 0.f;
      vs.y += val ? xv[j].y : 0.f;
    }
  }
  ((float2*)&vbuf[wave][0])[lane] = vs;
  __syncthreads();
  int d = threadIdx.x >> 1;
  int half = threadIdx.x & 1;
  u16x2 o;
#pragma unroll
  for (int j = 0; j < 2; ++j) o[j] = bf16_bits(vbuf[half * 2 + j][d]);
  *reinterpret_cast<u16x2*>(v_ct + ((size_t)b * D_DIM + d) * C_PAD + c0 + half * 2) = o;
}

// ------ kernel 3: cluster attention, LDS-staged K/V with double buffer -------
// Round-13 rocprof: 88us, MfmaUtil 4.2% — per-tile B-fragment loads from L2
// are scheduler-sunk next to their MFMAs (same disease as k_seg rounds 2-7):
// ~16 serialized ~300cy L2 latencies per tile. Fix: stage K-tile (64x128) and
// V-tile (128x64) into LDS via global_load_lds (zero VGPRs, all in flight),
// double-buffered so staging of jt+1 overlaps compute of jt; MFMA operands
// come from ds_read_b128 (~12cy). XOR swizzle (slot ^= row&7) applied on the
// pre-swizzled GLOBAL source (rule #21) kills the 256B/128B-stride bank
// conflicts. 4 waves share each staged tile (4x reuse vs round-13).
__global__ __launch_bounds__(256) void k_attn(const __hip_bfloat16* __restrict__ q_cb,
                                              const __hip_bfloat16* __restrict__ k_cb,
                                              const __hip_bfloat16* __restrict__ v_ct,
                                              const float* __restrict__ counts_f,
                                              float* __restrict__ v_out,
                                              float* __restrict__ a0_out) {
  __shared__ __align__(16) __hip_bfloat16 Kbuf[2][64][D_DIM];  // 32 KB
  __shared__ __align__(16) __hip_bfloat16 Vbuf[2][D_DIM][64];  // 32 KB
  __shared__ __align__(16) __hip_bfloat16 plds[4][16][88];     // 11 KB
  int b = blockIdx.x;
  int tile = blockIdx.y;
  int wave = threadIdx.x >> 6;
  int lane = threadIdx.x & 63;
  int l15 = lane & 15;
  int lhi = lane >> 4;
  int r0 = tile * 64 + wave * 16;

  const __hip_bfloat16* qb = q_cb + (size_t)b * C_PAD * D_DIM;
  const __hip_bfloat16* kb = k_cb + (size_t)b * C_PAD * D_DIM;
  const __hip_bfloat16* vb = v_ct + (size_t)b * D_DIM * C_PAD;
  const float* cnt = counts_f + (size_t)(b & (NB0 - 1)) * C_PAD;

  bf16x8 afrag[4];
#pragma unroll
  for (int ks = 0; ks < 4; ++ks)
    afrag[ks] = *(const bf16x8*)(qb + (size_t)(r0 + l15) * D_DIM + ks * 32 + lhi * 8);

  float lsum[4] = {0.f, 0.f, 0.f, 0.f};
  float a0v[4] = {0.f, 0.f, 0.f, 0.f};
  f32x4 oacc[8];
#pragma unroll
  for (int d = 0; d < 8; ++d) oacc[d] = f32x4{0.f, 0.f, 0.f, 0.f};

  // --- staging: wave issues instrs i = wave*4 .. wave*4+3 per tensor ---
  // K instr i covers rows 4i..4i+3 (4 x 256B); lane l -> row 4i+(l>>4),
  // source slot = (l&15) ^ (row&7)  (inverse-swizzled global source).
  // V instr i covers d-rows 8i..8i+7 (8 x 128B); lane l -> row 8i+(l>>3),
  // source slot = (l&7) ^ (row&7).
#define STAGE_KV(buf, jt)                                                      \
  {                                                                            \
    _Pragma("unroll") for (int ii = 0; ii < 4; ++ii) {                         \
      int i = wave * 4 + ii;                                                   \
      int r = i * 4 + (lane >> 4);                                             \
      int cs = (lane & 15) ^ (r & 7);                                          \
      __builtin_amdgcn_global_load_lds(                                        \
          (const void*)(kb + (size_t)((jt) * 64 + r) * D_DIM + cs * 8),        \
          (void*)&Kbuf[buf][i * 4][0], 16, 0, 0);                              \
    }                                                                          \
    _Pragma("unroll") for (int ii = 0; ii < 4; ++ii) {                         \
      int i = wave * 4 + ii;                                                   \
      int r = i * 8 + (lane >> 3);                                             \
      int cs = (lane & 7) ^ (r & 7);                                           \
      __builtin_amdgcn_global_load_lds(                                        \
          (const void*)(vb + (size_t)r * C_PAD + (jt) * 64 + cs * 8),          \
          (void*)&Vbuf[buf][i * 8][0], 16, 0, 0);                              \
    }                                                                          \
  }

  STAGE_KV(0, 0);
  asm volatile("s_waitcnt vmcnt(0)" ::: "memory");
  __syncthreads();

  int cur = 0;
  for (int jt = 0; jt < NTILE; ++jt) {
    if (jt + 1 < NTILE) STAGE_KV(cur ^ 1, jt + 1);

    f32x4 s[4];
#pragma unroll
    for (int js = 0; js < 4; ++js) {
      s[js] = f32x4{0.f, 0.f, 0.f, 0.f};
#pragma unroll
      for (int ks = 0; ks < 4; ++ks) {
        int slot = (ks * 4 + lhi) ^ (l15 & 7);
        bf16x8 bfrag = *(const bf16x8*)&Kbuf[cur][js * 16 + l15][slot * 8];
        s[js] = __builtin_amdgcn_mfma_f32_16x16x32_bf16(afrag[ks], bfrag, s[js], 0, 0, 0);
      }
    }
    float csub[4];
#pragma unroll
    for (int js = 0; js < 4; ++js) csub[js] = cnt[jt * 64 + js * 16 + l15];

    float ps[4][4];
#pragma unroll
    for (int r = 0; r < 4; ++r) {
#pragma unroll
      for (int js = 0; js < 4; ++js) {
        float p = __expf(s[js][r]);
        ps[js][r] = p;
        lsum[r] += p * csub[js];   // per-lane partial; reduced once at end
      }
    }
    if (jt == 0 && l15 == 0) {
#pragma unroll
      for (int r = 0; r < 4; ++r) a0v[r] = ps[0][r] * csub[0];
    }
#pragma unroll
    for (int js = 0; js < 4; ++js)
#pragma unroll
      for (int r = 0; r < 4; ++r)
        plds[wave][lhi * 4 + r][js * 16 + l15] = __float2bfloat16(ps[js][r]);
    bf16x8 pfrag[2];
#pragma unroll
    for (int k2 = 0; k2 < 2; ++k2)
      pfrag[k2] = *(const bf16x8*)&plds[wave][l15][k2 * 32 + lhi * 8];
#pragma unroll
    for (int d2 = 0; d2 < 8; ++d2) {
      f32x4 o = oacc[d2];
#pragma unroll
      for (int k2 = 0; k2 < 2; ++k2) {
        int slot = (k2 * 4 + lhi) ^ (l15 & 7);
        bf16x8 vfrag = *(const bf16x8*)&Vbuf[cur][d2 * 16 + l15][slot * 8];
        o = __builtin_amdgcn_mfma_f32_16x16x32_bf16(pfrag[k2], vfrag, o, 0, 0, 0);
      }
      oacc[d2] = o;
    }

    asm volatile("s_waitcnt vmcnt(0)" ::: "memory");  // next tile landed
    __syncthreads();                                  // all waves done with cur
    cur ^= 1;
  }

  // single row-sum reduction (rows live across the 16 lanes sharing lhi)
#pragma unroll
  for (int off = 1; off < 16; off <<= 1) {
#pragma unroll
    for (int r = 0; r < 4; ++r) lsum[r] += __shfl_xor(lsum[r], off, 64);
  }

  float inv[4];
#pragma unroll
  for (int r = 0; r < 4; ++r) inv[r] = 1.f / lsum[r];
  float* vo = v_out + (size_t)b * C_PAD * D_DIM;
#pragma unroll
  for (int r = 0; r < 4; ++r) {
    int row = r0 + lhi * 4 + r;
    if (row < C_REAL) {
#pragma unroll
      for (int d2 = 0; d2 < 8; ++d2)
        vo[(size_t)row * D_DIM + d2 * 16 + l15] = oacc[d2][r] * inv[r];
      if (l15 == 0) a0_out[(size_t)b * C_REAL + row] = a0v[r] * inv[r];
    }
  }
}

// ---------------- kernel 4: broadcast cluster outputs to tokens --------------
__global__ __launch_bounds__(256) void k_gather(const float* __restrict__ v_out,
                                                const int* __restrict__ clusters,
                                                float* __restrict__ out) {
  size_t idx = (size_t)blockIdx.x * 256 + threadIdx.x;
  int quad = (int)(idx & 31);
  size_t row = idx >> 5;
  int b = (int)(row >> 12);
  int n = (int)(row & (N_TOK - 1));
  int c = clusters[(size_t)(b & (NB0 - 1)) * N_TOK + n];
  const float4* src = (const float4*)(v_out + ((size_t)b * C_PAD + c) * D_DIM);
  ((float4*)(out + row * D_DIM))[quad] = src[quad];
}

extern "C" void kernel_launch(void* const* d_in, const int* in_sizes, int n_in,
                              void* d_out, int out_size, void* d_ws, size_t ws_size,
                              hipStream_t stream) {
  const float* q = (const float*)d_in[0];
  const float* k = (const float*)d_in[1];
  const float* v = (const float*)d_in[2];
  const int* clusters = (const int*)d_in[3];
  float* out = (float*)d_out;
  float* a0 = out + (size_t)B_TOT * N_TOK * D_DIM;

  char* ws = (char*)d_ws;
  float* counts_f = (float*)ws;
  float* wts = counts_f + NB0 * C_PAD;
  int* offs_g = (int*)(wts + NB0 * C_PAD);
  int* sorted = offs_g + NB0 * C_PAD;
  __hip_bfloat16* q_cb = (__hip_bfloat16*)(sorted + NB0 * N_TOK);
  size_t cbElems = (size_t)B_TOT * C_PAD * D_DIM;
  __hip_bfloat16* k_cb = q_cb + cbElems;
  __hip_bfloat16* v_ct = k_cb + cbElems;
  float* v_out = (float*)(v_ct + cbElems);

  k_setup<<<NB0, 576, 0, stream>>>(clusters, counts_f, wts, offs_g, sorted);

  dim3 gs(B_TOT, C_PAD / CPB);
  k_seg1<1><<<gs, 256, 0, stream>>>(q, sorted, offs_g, wts, q_cb);
  k_seg1<1><<<gs, 256, 0, stream>>>(k, sorted, offs_g, wts, k_cb);
  k_seg_v<<<gs, 256, 0, stream>>>(v, sorted, offs_g, v_ct);

  k_attn<<<dim3(B_TOT, NTILE), 256, 0, stream>>>(q_cb, k_cb, v_ct, counts_f, v_out, a0);

  k_gather<<<(B_TOT * N_TOK * 32) / 256, 256, 0, stream>>>(v_out, clusters, out);
}

// Round 15
// 182.516 us; speedup vs baseline: 1.3661x; 1.0342x over previous
//
#include <hip/hip_runtime.h>
#include <hip/hip_bf16.h>

#define B_TOT 64
#define NB0 8
#define N_TOK 4096
#define D_DIM 128
#define C_REAL 513
#define C_PAD 576
#define NTILE 9   // C_PAD / 64
#define CPB 4     // clusters per segsum block (1 per wave, 4 waves of 256)

typedef __bf16 bf16x8 __attribute__((ext_vector_type(8)));
typedef float f32x4 __attribute__((ext_vector_type(4)));
typedef unsigned short u16x2 __attribute__((ext_vector_type(2)));

static __device__ __forceinline__ unsigned short bf16_bits(float x) {
  __hip_bfloat16 h = __float2bfloat16(x);
  return *reinterpret_cast<unsigned short*>(&h);
}

// ------ kernel 1: per-b0 bincount, weights, shuffle-scan, counting-sort ------
__global__ __launch_bounds__(576) void k_setup(const int* __restrict__ clusters,
                                               float* __restrict__ counts_f,
                                               float* __restrict__ wts,
                                               int* __restrict__ offs_g,
                                               int* __restrict__ sorted) {
  __shared__ int cnt[C_PAD];
  __shared__ int scan[C_PAD];
  __shared__ int rank[C_PAD];
  __shared__ int wsum[9], wpre[9];
  int b0 = blockIdx.x;
  int t = threadIdx.x;
  int lane = t & 63;
  int w = t >> 6;  // 0..8
  cnt[t] = 0;
  rank[t] = 0;
  __syncthreads();
  for (int n = t; n < N_TOK; n += 576)
    atomicAdd(&cnt[clusters[b0 * N_TOK + n]], 1);
  __syncthreads();
  int myc = cnt[t];
  int v = myc;
#pragma unroll
  for (int off = 1; off < 64; off <<= 1) {
    int u = __shfl_up(v, off, 64);
    if (lane >= off) v += u;
  }
  if (lane == 63) wsum[w] = v;
  __syncthreads();
  if (t < 9) {
    int s = 0;
    for (int i = 0; i < t; ++i) s += wsum[i];
    wpre[t] = s;
  }
  __syncthreads();
  int inc = v + wpre[w];   // inclusive scan over all 576
  scan[t] = inc;
  offs_g[b0 * C_PAD + t] = inc - myc;
  counts_f[b0 * C_PAD + t] = (t < C_REAL) ? (float)myc : 0.0f;
  wts[b0 * C_PAD + t] = (t < C_REAL && myc > 0) ? 1.0f / (float)myc : 0.0f;
  __syncthreads();
  for (int n = t; n < N_TOK; n += 576) {
    int c = clusters[b0 * N_TOK + n];
    int pos = scan[c] - cnt[c] + atomicAdd(&rank[c], 1);
    sorted[b0 * N_TOK + pos] = n;
  }
}

// ------- kernel 2a/2b: per-tensor sorted-gather segmented sums (q,k) ---------
// ~110-140us aggregate = HW wall for the 402MB permutation gather (rounds 2-9).
template <int WEIGHTED>
__global__ __launch_bounds__(256) void k_seg1(const float* __restrict__ src,
                                              const int* __restrict__ sorted,
                                              const int* __restrict__ offs_g,
                                              const float* __restrict__ wts,
                                              __hip_bfloat16* __restrict__ dst) {
  int b = blockIdx.x;
  int b0 = b & (NB0 - 1);
  int c = blockIdx.y * CPB + (threadIdx.x >> 6);
  int lane = threadIdx.x & 63;
  const int* sidx = sorted + (size_t)b0 * N_TOK;
  const float* sb = src + (size_t)b * N_TOK * D_DIM;

  float2 s2 = {0.f, 0.f};
  if (c < C_REAL) {
    int start = offs_g[b0 * C_PAD + c];
    int count = offs_g[b0 * C_PAD + c + 1] - start;
    int l8 = lane & 7;
    int tn = sidx[start + ((l8 < count) ? l8 : 0)];
    float2 xv[8];
#pragma unroll
    for (int j = 0; j < 8; ++j) {
      int n = __shfl(tn, j, 64);
      xv[j] = ((const float2*)(sb + (size_t)n * D_DIM))[lane];
    }
#pragma unroll
    for (int j = 0; j < 8; ++j) {
      bool val = (j < count);
      s2.x += val ? xv[j].x : 0.f;
      s2.y += val ? xv[j].y : 0.f;
    }
    if (WEIGHTED) {
      float w = wts[b0 * C_PAD + c];
      s2.x *= w; s2.y *= w;
    }
  }
  __hip_bfloat162 o;
  o.x = __float2bfloat16(s2.x);
  o.y = __float2bfloat16(s2.y);
  *reinterpret_cast<__hip_bfloat162*>(dst + ((size_t)b * C_PAD + c) * D_DIM + lane * 2) = o;
}

// ------- kernel 2c: v tensor — raw sums, transposed output [b][d][c] ---------
__global__ __launch_bounds__(256) void k_seg_v(const float* __restrict__ v,
                                               const int* __restrict__ sorted,
                                               const int* __restrict__ offs_g,
                                               __hip_bfloat16* __restrict__ v_ct) {
  __shared__ float vbuf[CPB][D_DIM];  // 2 KB
  int b = blockIdx.x;
  int b0 = b & (NB0 - 1);
  int c0 = blockIdx.y * CPB;
  int wave = threadIdx.x >> 6;
  int lane = threadIdx.x & 63;
  int c = c0 + wave;
  const int* sidx = sorted + (size_t)b0 * N_TOK;
  const float* vb = v + (size_t)b * N_TOK * D_DIM;

  float2 vs = {0.f, 0.f};
  if (c < C_REAL) {
    int start = offs_g[b0 * C_PAD + c];
    int count = offs_g[b0 * C_PAD + c + 1] - start;
    int l8 = lane & 7;
    int tn = sidx[start + ((l8 < count) ? l8 : 0)];
    float2 xv[8];
#pragma unroll
    for (int j = 0; j < 8; ++j) {
      int n = __shfl(tn, j, 64);
      xv[j] = ((const float2*)(vb + (size_t)n * D_DIM))[lane];
    }
#pragma unroll
    for (int j = 0; j < 8; ++j) {
      bool val = (j < count);
      vs.x += val ? xv[j].x : 0.f;
      vs.y += val ? xv[j].y : 0.f;
    }
  }
  ((float2*)&vbuf[wave][0])[lane] = vs;
  __syncthreads();
  int d = threadIdx.x >> 1;
  int half = threadIdx.x & 1;
  u16x2 o;
#pragma unroll
  for (int j = 0; j < 2; ++j) o[j] = bf16_bits(vbuf[half * 2 + j][d]);
  *reinterpret_cast<u16x2*>(v_ct + ((size_t)b * D_DIM + d) * C_PAD + c0 + half * 2) = o;
}

// ------ kernel 3: cluster attention + fused token broadcast ------------------
// LDS-staged double-buffered K/V (round-14: 88->43us, scheduler can't sink
// DMA loads). NEW: k_gather fused into the epilogue — each block owns 64
// cluster rows; stage them in LDS (reuse Kbuf: 64x128 f32 = 32KB) and write
// each row to its <=8 token positions as full-wave 512B coalesced stores.
// Deletes the k_gather kernel + v_out round-trip (19MB write + 19MB random
// read); adds 134MB fire-and-forget stores here.
__global__ __launch_bounds__(256) void k_attn(const __hip_bfloat16* __restrict__ q_cb,
                                              const __hip_bfloat16* __restrict__ k_cb,
                                              const __hip_bfloat16* __restrict__ v_ct,
                                              const float* __restrict__ counts_f,
                                              const int* __restrict__ sorted,
                                              const int* __restrict__ offs_g,
                                              float* __restrict__ out,
                                              float* __restrict__ a0_out) {
  __shared__ __align__(16) __hip_bfloat16 Kbuf[2][64][D_DIM];  // 32 KB
  __shared__ __align__(16) __hip_bfloat16 Vbuf[2][D_DIM][64];  // 32 KB
  __shared__ __align__(16) __hip_bfloat16 plds[4][16][88];     // 11 KB
  int b = blockIdx.x;
  int b0 = b & (NB0 - 1);
  int tile = blockIdx.y;
  int wave = threadIdx.x >> 6;
  int lane = threadIdx.x & 63;
  int l15 = lane & 15;
  int lhi = lane >> 4;
  int r0 = tile * 64 + wave * 16;

  const __hip_bfloat16* qb = q_cb + (size_t)b * C_PAD * D_DIM;
  const __hip_bfloat16* kb = k_cb + (size_t)b * C_PAD * D_DIM;
  const __hip_bfloat16* vb = v_ct + (size_t)b * D_DIM * C_PAD;
  const float* cnt = counts_f + (size_t)b0 * C_PAD;

  bf16x8 afrag[4];
#pragma unroll
  for (int ks = 0; ks < 4; ++ks)
    afrag[ks] = *(const bf16x8*)(qb + (size_t)(r0 + l15) * D_DIM + ks * 32 + lhi * 8);

  float lsum[4] = {0.f, 0.f, 0.f, 0.f};
  float a0v[4] = {0.f, 0.f, 0.f, 0.f};
  f32x4 oacc[8];
#pragma unroll
  for (int d = 0; d < 8; ++d) oacc[d] = f32x4{0.f, 0.f, 0.f, 0.f};

#define STAGE_KV(buf, jt)                                                      \
  {                                                                            \
    _Pragma("unroll") for (int ii = 0; ii < 4; ++ii) {                         \
      int i = wave * 4 + ii;                                                   \
      int r = i * 4 + (lane >> 4);                                             \
      int cs = (lane & 15) ^ (r & 7);                                          \
      __builtin_amdgcn_global_load_lds(                                        \
          (const void*)(kb + (size_t)((jt) * 64 + r) * D_DIM + cs * 8),        \
          (void*)&Kbuf[buf][i * 4][0], 16, 0, 0);                              \
    }                                                                          \
    _Pragma("unroll") for (int ii = 0; ii < 4; ++ii) {                         \
      int i = wave * 4 + ii;                                                   \
      int r = i * 8 + (lane >> 3);                                             \
      int cs = (lane & 7) ^ (r & 7);                                           \
      __builtin_amdgcn_global_load_lds(                                        \
          (const void*)(vb + (size_t)r * C_PAD + (jt) * 64 + cs * 8),          \
          (void*)&Vbuf[buf][i * 8][0], 16, 0, 0);                              \
    }                                                                          \
  }

  STAGE_KV(0, 0);
  asm volatile("s_waitcnt vmcnt(0)" ::: "memory");
  __syncthreads();

  int cur = 0;
  for (int jt = 0; jt < NTILE; ++jt) {
    if (jt + 1 < NTILE) STAGE_KV(cur ^ 1, jt + 1);

    f32x4 s[4];
#pragma unroll
    for (int js = 0; js < 4; ++js) {
      s[js] = f32x4{0.f, 0.f, 0.f, 0.f};
#pragma unroll
      for (int ks = 0; ks < 4; ++ks) {
        int slot = (ks * 4 + lhi) ^ (l15 & 7);
        bf16x8 bfrag = *(const bf16x8*)&Kbuf[cur][js * 16 + l15][slot * 8];
        s[js] = __builtin_amdgcn_mfma_f32_16x16x32_bf16(afrag[ks], bfrag, s[js], 0, 0, 0);
      }
    }
    float csub[4];
#pragma unroll
    for (int js = 0; js < 4; ++js) csub[js] = cnt[jt * 64 + js * 16 + l15];

    float ps[4][4];
#pragma unroll
    for (int r = 0; r < 4; ++r) {
#pragma unroll
      for (int js = 0; js < 4; ++js) {
        float p = __expf(s[js][r]);
        ps[js][r] = p;
        lsum[r] += p * csub[js];   // per-lane partial; reduced once at end
      }
    }
    if (jt == 0 && l15 == 0) {
#pragma unroll
      for (int r = 0; r < 4; ++r) a0v[r] = ps[0][r] * csub[0];
    }
#pragma unroll
    for (int js = 0; js < 4; ++js)
#pragma unroll
      for (int r = 0; r < 4; ++r)
        plds[wave][lhi * 4 + r][js * 16 + l15] = __float2bfloat16(ps[js][r]);
    bf16x8 pfrag[2];
#pragma unroll
    for (int k2 = 0; k2 < 2; ++k2)
      pfrag[k2] = *(const bf16x8*)&plds[wave][l15][k2 * 32 + lhi * 8];
#pragma unroll
    for (int d2 = 0; d2 < 8; ++d2) {
      f32x4 o = oacc[d2];
#pragma unroll
      for (int k2 = 0; k2 < 2; ++k2) {
        int slot = (k2 * 4 + lhi) ^ (l15 & 7);
        bf16x8 vfrag = *(const bf16x8*)&Vbuf[cur][d2 * 16 + l15][slot * 8];
        o = __builtin_amdgcn_mfma_f32_16x16x32_bf16(pfrag[k2], vfrag, o, 0, 0, 0);
      }
      oacc[d2] = o;
    }

    asm volatile("s_waitcnt vmcnt(0)" ::: "memory");  // next tile landed
    __syncthreads();                                  // all waves done with cur
    cur ^= 1;
  }

  // row-sum reduction (rows live across the 16 lanes sharing lhi)
#pragma unroll
  for (int off = 1; off < 16; off <<= 1) {
#pragma unroll
    for (int r = 0; r < 4; ++r) lsum[r] += __shfl_xor(lsum[r], off, 64);
  }
  float inv[4];
#pragma unroll
  for (int r = 0; r < 4; ++r) inv[r] = 1.f / lsum[r];

  // a0 output
#pragma unroll
  for (int r = 0; r < 4; ++r) {
    int row = r0 + lhi * 4 + r;
    if (row < C_REAL && l15 == 0)
      a0_out[(size_t)b * C_REAL + row] = a0v[r] * inv[r];
  }

  // --- fused broadcast: stage 64 output rows in LDS (reuse Kbuf), then write
  // each row to its <=8 token positions as full-wave 512B stores ---
  float* rowbuf = (float*)&Kbuf[0][0][0];  // 64 rows x 128 f32 = 32 KB
  __syncthreads();                          // Kbuf no longer needed
#pragma unroll
  for (int d2 = 0; d2 < 8; ++d2)
#pragma unroll
    for (int r = 0; r < 4; ++r)
      rowbuf[(wave * 16 + lhi * 4 + r) * D_DIM + d2 * 16 + l15] = oacc[d2][r] * inv[r];
  __syncthreads();

  const int* offs = offs_g + b0 * C_PAD;
  const int* sidx = sorted + (size_t)b0 * N_TOK;
  float* outb = out + (size_t)b * N_TOK * D_DIM;
  for (int rr = 0; rr < 16; ++rr) {
    int c = tile * 64 + wave * 16 + rr;
    if (c >= C_REAL) break;                 // wave-uniform
    int start = offs[c];
    int count = offs[c + 1] - start;
    int l8 = lane & 7;
    int tn = sidx[start + ((l8 < count) ? l8 : 0)];
    float2 val = ((const float2*)(rowbuf + (wave * 16 + rr) * D_DIM))[lane];
#pragma unroll
    for (int j = 0; j < 8; ++j) {
      if (j < count) {                      // wave-uniform
        int n = __shfl(tn, j, 64);
        ((float2*)(outb + (size_t)n * D_DIM))[lane] = val;
      }
    }
  }
}

extern "C" void kernel_launch(void* const* d_in, const int* in_sizes, int n_in,
                              void* d_out, int out_size, void* d_ws, size_t ws_size,
                              hipStream_t stream) {
  const float* q = (const float*)d_in[0];
  const float* k = (const float*)d_in[1];
  const float* v = (const float*)d_in[2];
  const int* clusters = (const int*)d_in[3];
  float* out = (float*)d_out;
  float* a0 = out + (size_t)B_TOT * N_TOK * D_DIM;

  char* ws = (char*)d_ws;
  float* counts_f = (float*)ws;
  float* wts = counts_f + NB0 * C_PAD;
  int* offs_g = (int*)(wts + NB0 * C_PAD);
  int* sorted = offs_g + NB0 * C_PAD;
  __hip_bfloat16* q_cb = (__hip_bfloat16*)(sorted + NB0 * N_TOK);
  size_t cbElems = (size_t)B_TOT * C_PAD * D_DIM;
  __hip_bfloat16* k_cb = q_cb + cbElems;
  __hip_bfloat16* v_ct = k_cb + cbElems;

  k_setup<<<NB0, 576, 0, stream>>>(clusters, counts_f, wts, offs_g, sorted);

  dim3 gs(B_TOT, C_PAD / CPB);
  k_seg1<1><<<gs, 256, 0, stream>>>(q, sorted, offs_g, wts, q_cb);
  k_seg1<1><<<gs, 256, 0, stream>>>(k, sorted, offs_g, wts, k_cb);
  k_seg_v<<<gs, 256, 0, stream>>>(v, sorted, offs_g, v_ct);

  k_attn<<<dim3(B_TOT, NTILE), 256, 0, stream>>>(q_cb, k_cb, v_ct, counts_f,
                                                 sorted, offs_g, out, a0);
}

// Round 16
// 170.155 us; speedup vs baseline: 1.4654x; 1.0726x over previous
//
#include <hip/hip_runtime.h>
#include <hip/hip_bf16.h>

#define B_TOT 64
#define NB0 8
#define N_TOK 4096
#define D_DIM 128
#define C_REAL 513
#define C_PAD 576
#define NTILE 9   // C_PAD / 64
#define CPB 4     // clusters per segsum block (1 per wave, 4 waves of 256)

typedef __bf16 bf16x8 __attribute__((ext_vector_type(8)));
typedef float f32x4 __attribute__((ext_vector_type(4)));
typedef unsigned short u16x2 __attribute__((ext_vector_type(2)));

static __device__ __forceinline__ unsigned short bf16_bits(float x) {
  __hip_bfloat16 h = __float2bfloat16(x);
  return *reinterpret_cast<unsigned short*>(&h);
}

// ------ kernel 1: per-b0 bincount, weights, shuffle-scan, counting-sort ------
__global__ __launch_bounds__(576) void k_setup(const int* __restrict__ clusters,
                                               float* __restrict__ counts_f,
                                               float* __restrict__ wts,
                                               int* __restrict__ offs_g,
                                               int* __restrict__ sorted) {
  __shared__ int cnt[C_PAD];
  __shared__ int scan[C_PAD];
  __shared__ int rank[C_PAD];
  __shared__ int wsum[9], wpre[9];
  int b0 = blockIdx.x;
  int t = threadIdx.x;
  int lane = t & 63;
  int w = t >> 6;  // 0..8
  cnt[t] = 0;
  rank[t] = 0;
  __syncthreads();
  for (int n = t; n < N_TOK; n += 576)
    atomicAdd(&cnt[clusters[b0 * N_TOK + n]], 1);
  __syncthreads();
  int myc = cnt[t];
  int v = myc;
#pragma unroll
  for (int off = 1; off < 64; off <<= 1) {
    int u = __shfl_up(v, off, 64);
    if (lane >= off) v += u;
  }
  if (lane == 63) wsum[w] = v;
  __syncthreads();
  if (t < 9) {
    int s = 0;
    for (int i = 0; i < t; ++i) s += wsum[i];
    wpre[t] = s;
  }
  __syncthreads();
  int inc = v + wpre[w];   // inclusive scan over all 576
  scan[t] = inc;
  offs_g[b0 * C_PAD + t] = inc - myc;
  counts_f[b0 * C_PAD + t] = (t < C_REAL) ? (float)myc : 0.0f;
  wts[b0 * C_PAD + t] = (t < C_REAL && myc > 0) ? 1.0f / (float)myc : 0.0f;
  __syncthreads();
  for (int n = t; n < N_TOK; n += 576) {
    int c = clusters[b0 * N_TOK + n];
    int pos = scan[c] - cnt[c] + atomicAdd(&rank[c], 1);
    sorted[b0 * N_TOK + pos] = n;
  }
}

// ------- kernel 2a/2b: per-tensor sorted-gather segmented sums (q,k) ---------
// ~110us aggregate = DRAM wall for the 402MB permutation gather of 512B rows
// (rounds 2-9: reg/asm/DMA/scatter all equal or worse). Left as-is.
template <int WEIGHTED>
__global__ __launch_bounds__(256) void k_seg1(const float* __restrict__ src,
                                              const int* __restrict__ sorted,
                                              const int* __restrict__ offs_g,
                                              const float* __restrict__ wts,
                                              __hip_bfloat16* __restrict__ dst) {
  int b = blockIdx.x;
  int b0 = b & (NB0 - 1);
  int c = blockIdx.y * CPB + (threadIdx.x >> 6);
  int lane = threadIdx.x & 63;
  const int* sidx = sorted + (size_t)b0 * N_TOK;
  const float* sb = src + (size_t)b * N_TOK * D_DIM;

  float2 s2 = {0.f, 0.f};
  if (c < C_REAL) {
    int start = offs_g[b0 * C_PAD + c];
    int count = offs_g[b0 * C_PAD + c + 1] - start;
    int l8 = lane & 7;
    int tn = sidx[start + ((l8 < count) ? l8 : 0)];
    float2 xv[8];
#pragma unroll
    for (int j = 0; j < 8; ++j) {
      int n = __shfl(tn, j, 64);
      xv[j] = ((const float2*)(sb + (size_t)n * D_DIM))[lane];
    }
#pragma unroll
    for (int j = 0; j < 8; ++j) {
      bool val = (j < count);
      s2.x += val ? xv[j].x : 0.f;
      s2.y += val ? xv[j].y : 0.f;
    }
    if (WEIGHTED) {
      float w = wts[b0 * C_PAD + c];
      s2.x *= w; s2.y *= w;
    }
  }
  __hip_bfloat162 o;
  o.x = __float2bfloat16(s2.x);
  o.y = __float2bfloat16(s2.y);
  *reinterpret_cast<__hip_bfloat162*>(dst + ((size_t)b * C_PAD + c) * D_DIM + lane * 2) = o;
}

// ------- kernel 2c: v tensor — raw sums, transposed output [b][d][c] ---------
__global__ __launch_bounds__(256) void k_seg_v(const float* __restrict__ v,
                                               const int* __restrict__ sorted,
                                               const int* __restrict__ offs_g,
                                               __hip_bfloat16* __restrict__ v_ct) {
  __shared__ float vbuf[CPB][D_DIM];  // 2 KB
  int b = blockIdx.x;
  int b0 = b & (NB0 - 1);
  int c0 = blockIdx.y * CPB;
  int wave = threadIdx.x >> 6;
  int lane = threadIdx.x & 63;
  int c = c0 + wave;
  const int* sidx = sorted + (size_t)b0 * N_TOK;
  const float* vb = v + (size_t)b * N_TOK * D_DIM;

  float2 vs = {0.f, 0.f};
  if (c < C_REAL) {
    int start = offs_g[b0 * C_PAD + c];
    int count = offs_g[b0 * C_PAD + c + 1] - start;
    int l8 = lane & 7;
    int tn = sidx[start + ((l8 < count) ? l8 : 0)];
    float2 xv[8];
#pragma unroll
    for (int j = 0; j < 8; ++j) {
      int n = __shfl(tn, j, 64);
      xv[j] = ((const float2*)(vb + (size_t)n * D_DIM))[lane];
    }
#pragma unroll
    for (int j = 0; j < 8; ++j) {
      bool val = (j < count);
      vs.x += val ? xv[j].x : 0.f;
      vs.y += val ? xv[j].y : 0.f;
    }
  }
  ((float2*)&vbuf[wave][0])[lane] = vs;
  __syncthreads();
  int d = threadIdx.x >> 1;
  int half = threadIdx.x & 1;
  u16x2 o;
#pragma unroll
  for (int j = 0; j < 2; ++j) o[j] = bf16_bits(vbuf[half * 2 + j][d]);
  *reinterpret_cast<u16x2*>(v_ct + ((size_t)b * D_DIM + d) * C_PAD + c0 + half * 2) = o;
}

// ------ kernel 3: cluster attention + fused token broadcast ------------------
// Round-15 ledger: attn+broadcast ~65us, MfmaUtil low — latency-bound at
// 2 blocks/CU (LDS 75KB dbuf). Fix: SINGLE-buffer K/V in a unified 43KB smem
// region -> 3 blocks/CU (576 blocks nearly all co-resident); per-tile
// {barrier, stage, vmcnt(0), barrier, compute} — lost intra-block prefetch
// is covered by the extra resident block. rowbuf (64x128 f32, 32KB) overlays
// the K+V region after the last tile.
__global__ __launch_bounds__(256) void k_attn(const __hip_bfloat16* __restrict__ q_cb,
                                              const __hip_bfloat16* __restrict__ k_cb,
                                              const __hip_bfloat16* __restrict__ v_ct,
                                              const float* __restrict__ counts_f,
                                              const int* __restrict__ sorted,
                                              const int* __restrict__ offs_g,
                                              float* __restrict__ out,
                                              float* __restrict__ a0_out) {
  __shared__ __align__(16) char smem[44032];  // 43 KB -> 3 blocks/CU
  __hip_bfloat16 (*Kbuf)[D_DIM] = (__hip_bfloat16(*)[D_DIM])smem;          // [64][128]
  __hip_bfloat16 (*Vbuf)[64] = (__hip_bfloat16(*)[64])(smem + 16384);      // [128][64]
  __hip_bfloat16 (*plds)[16][88] = (__hip_bfloat16(*)[16][88])(smem + 32768);
  float* rowbuf = (float*)smem;               // overlays K+V after last tile

  int b = blockIdx.x;
  int b0 = b & (NB0 - 1);
  int tile = blockIdx.y;
  int wave = threadIdx.x >> 6;
  int lane = threadIdx.x & 63;
  int l15 = lane & 15;
  int lhi = lane >> 4;
  int r0 = tile * 64 + wave * 16;

  const __hip_bfloat16* qb = q_cb + (size_t)b * C_PAD * D_DIM;
  const __hip_bfloat16* kb = k_cb + (size_t)b * C_PAD * D_DIM;
  const __hip_bfloat16* vb = v_ct + (size_t)b * D_DIM * C_PAD;
  const float* cnt = counts_f + (size_t)b0 * C_PAD;

  bf16x8 afrag[4];
#pragma unroll
  for (int ks = 0; ks < 4; ++ks)
    afrag[ks] = *(const bf16x8*)(qb + (size_t)(r0 + l15) * D_DIM + ks * 32 + lhi * 8);

  float lsum[4] = {0.f, 0.f, 0.f, 0.f};
  float a0v[4] = {0.f, 0.f, 0.f, 0.f};
  f32x4 oacc[8];
#pragma unroll
  for (int d = 0; d < 8; ++d) oacc[d] = f32x4{0.f, 0.f, 0.f, 0.f};

#define STAGE_KV(jt)                                                           \
  {                                                                            \
    _Pragma("unroll") for (int ii = 0; ii < 4; ++ii) {                         \
      int i = wave * 4 + ii;                                                   \
      int r = i * 4 + (lane >> 4);                                             \
      int cs = (lane & 15) ^ (r & 7);                                          \
      __builtin_amdgcn_global_load_lds(                                        \
          (const void*)(kb + (size_t)((jt) * 64 + r) * D_DIM + cs * 8),        \
          (void*)&Kbuf[i * 4][0], 16, 0, 0);                                   \
    }                                                                          \
    _Pragma("unroll") for (int ii = 0; ii < 4; ++ii) {                         \
      int i = wave * 4 + ii;                                                   \
      int r = i * 8 + (lane >> 3);                                             \
      int cs = (lane & 7) ^ (r & 7);                                           \
      __builtin_amdgcn_global_load_lds(                                        \
          (const void*)(vb + (size_t)r * C_PAD + (jt) * 64 + cs * 8),          \
          (void*)&Vbuf[i * 8][0], 16, 0, 0);                                   \
    }                                                                          \
  }

  for (int jt = 0; jt < NTILE; ++jt) {
    __syncthreads();                                  // all waves done reading
    STAGE_KV(jt);
    asm volatile("s_waitcnt vmcnt(0)" ::: "memory");  // my loads landed
    __syncthreads();                                  // everyone's landed

    f32x4 s[4];
#pragma unroll
    for (int js = 0; js < 4; ++js) {
      s[js] = f32x4{0.f, 0.f, 0.f, 0.f};
#pragma unroll
      for (int ks = 0; ks < 4; ++ks) {
        int slot = (ks * 4 + lhi) ^ (l15 & 7);
        bf16x8 bfrag = *(const bf16x8*)&Kbuf[js * 16 + l15][slot * 8];
        s[js] = __builtin_amdgcn_mfma_f32_16x16x32_bf16(afrag[ks], bfrag, s[js], 0, 0, 0);
      }
    }
    float csub[4];
#pragma unroll
    for (int js = 0; js < 4; ++js) csub[js] = cnt[jt * 64 + js * 16 + l15];

    float ps[4][4];
#pragma unroll
    for (int r = 0; r < 4; ++r) {
#pragma unroll
      for (int js = 0; js < 4; ++js) {
        float p = __expf(s[js][r]);
        ps[js][r] = p;
        lsum[r] += p * csub[js];   // per-lane partial; reduced once at end
      }
    }
    if (jt == 0 && l15 == 0) {
#pragma unroll
      for (int r = 0; r < 4; ++r) a0v[r] = ps[0][r] * csub[0];
    }
#pragma unroll
    for (int js = 0; js < 4; ++js)
#pragma unroll
      for (int r = 0; r < 4; ++r)
        plds[wave][lhi * 4 + r][js * 16 + l15] = __float2bfloat16(ps[js][r]);
    bf16x8 pfrag[2];
#pragma unroll
    for (int k2 = 0; k2 < 2; ++k2)
      pfrag[k2] = *(const bf16x8*)&plds[wave][l15][k2 * 32 + lhi * 8];
#pragma unroll
    for (int d2 = 0; d2 < 8; ++d2) {
      f32x4 o = oacc[d2];
#pragma unroll
      for (int k2 = 0; k2 < 2; ++k2) {
        int slot = (k2 * 4 + lhi) ^ (l15 & 7);
        bf16x8 vfrag = *(const bf16x8*)&Vbuf[d2 * 16 + l15][slot * 8];
        o = __builtin_amdgcn_mfma_f32_16x16x32_bf16(pfrag[k2], vfrag, o, 0, 0, 0);
      }
      oacc[d2] = o;
    }
  }

  // row-sum reduction (rows live across the 16 lanes sharing lhi)
#pragma unroll
  for (int off = 1; off < 16; off <<= 1) {
#pragma unroll
    for (int r = 0; r < 4; ++r) lsum[r] += __shfl_xor(lsum[r], off, 64);
  }
  float inv[4];
#pragma unroll
  for (int r = 0; r < 4; ++r) inv[r] = 1.f / lsum[r];

  // a0 output
#pragma unroll
  for (int r = 0; r < 4; ++r) {
    int row = r0 + lhi * 4 + r;
    if (row < C_REAL && l15 == 0)
      a0_out[(size_t)b * C_REAL + row] = a0v[r] * inv[r];
  }

  // --- fused broadcast: stage 64 output rows in LDS (overlay K+V), then write
  // each row to its <=8 token positions as full-wave 512B stores ---
  __syncthreads();                          // K/V no longer needed
#pragma unroll
  for (int d2 = 0; d2 < 8; ++d2)
#pragma unroll
    for (int r = 0; r < 4; ++r)
      rowbuf[(wave * 16 + lhi * 4 + r) * D_DIM + d2 * 16 + l15] = oacc[d2][r] * inv[r];
  __syncthreads();

  const int* offs = offs_g + b0 * C_PAD;
  const int* sidx = sorted + (size_t)b0 * N_TOK;
  float* outb = out + (size_t)b * N_TOK * D_DIM;
  for (int rr = 0; rr < 16; ++rr) {
    int c = tile * 64 + wave * 16 + rr;
    if (c >= C_REAL) break;                 // wave-uniform
    int start = offs[c];
    int count = offs[c + 1] - start;
    int l8 = lane & 7;
    int tn = sidx[start + ((l8 < count) ? l8 : 0)];
    float2 val = ((const float2*)(rowbuf + (wave * 16 + rr) * D_DIM))[lane];
#pragma unroll
    for (int j = 0; j < 8; ++j) {
      if (j < count) {                      // wave-uniform
        int n = __shfl(tn, j, 64);
        ((float2*)(outb + (size_t)n * D_DIM))[lane] = val;
      }
    }
  }
}

extern "C" void kernel_launch(void* const* d_in, const int* in_sizes, int n_in,
                              void* d_out, int out_size, void* d_ws, size_t ws_size,
                              hipStream_t stream) {
  const float* q = (const float*)d_in[0];
  const float* k = (const float*)d_in[1];
  const float* v = (const float*)d_in[2];
  const int* clusters = (const int*)d_in[3];
  float* out = (float*)d_out;
  float* a0 = out + (size_t)B_TOT * N_TOK * D_DIM;

  char* ws = (char*)d_ws;
  float* counts_f = (float*)ws;
  float* wts = counts_f + NB0 * C_PAD;
  int* offs_g = (int*)(wts + NB0 * C_PAD);
  int* sorted = offs_g + NB0 * C_PAD;
  __hip_bfloat16* q_cb = (__hip_bfloat16*)(sorted + NB0 * N_TOK);
  size_t cbElems = (size_t)B_TOT * C_PAD * D_DIM;
  __hip_bfloat16* k_cb = q_cb + cbElems;
  __hip_bfloat16* v_ct = k_cb + cbElems;

  k_setup<<<NB0, 576, 0, stream>>>(clusters, counts_f, wts, offs_g, sorted);

  dim3 gs(B_TOT, C_PAD / CPB);
  k_seg1<1><<<gs, 256, 0, stream>>>(q, sorted, offs_g, wts, q_cb);
  k_seg1<1><<<gs, 256, 0, stream>>>(k, sorted, offs_g, wts, k_cb);
  k_seg_v<<<gs, 256, 0, stream>>>(v, sorted, offs_g, v_ct);

  k_attn<<<dim3(B_TOT, NTILE), 256, 0, stream>>>(q_cb, k_cb, v_ct, counts_f,
                                                 sorted, offs_g, out, a0);
}

// Round 17
// 162.989 us; speedup vs baseline: 1.5298x; 1.0440x over previous
//
#include <hip/hip_runtime.h>
#include <hip/hip_bf16.h>

#define B_TOT 64
#define NB0 8
#define N_TOK 4096
#define D_DIM 128
#define C_REAL 513
#define C_PAD 576
#define NTILE 9   // C_PAD / 64
#define CPB 4     // clusters per segsum block (1 per wave, 4 waves of 256)

typedef __bf16 bf16x8 __attribute__((ext_vector_type(8)));
typedef float f32x4 __attribute__((ext_vector_type(4)));
typedef unsigned short u16x2 __attribute__((ext_vector_type(2)));

static __device__ __forceinline__ unsigned short bf16_bits(float x) {
  __hip_bfloat16 h = __float2bfloat16(x);
  return *reinterpret_cast<unsigned short*>(&h);
}

// ------ kernel 1: per-b0 bincount, weights, shuffle-scan, counting-sort ------
__global__ __launch_bounds__(576) void k_setup(const int* __restrict__ clusters,
                                               float* __restrict__ counts_f,
                                               float* __restrict__ wts,
                                               int* __restrict__ offs_g,
                                               int* __restrict__ sorted) {
  __shared__ int cnt[C_PAD];
  __shared__ int scan[C_PAD];
  __shared__ int rank[C_PAD];
  __shared__ int wsum[9], wpre[9];
  int b0 = blockIdx.x;
  int t = threadIdx.x;
  int lane = t & 63;
  int w = t >> 6;  // 0..8
  cnt[t] = 0;
  rank[t] = 0;
  __syncthreads();
  for (int n = t; n < N_TOK; n += 576)
    atomicAdd(&cnt[clusters[b0 * N_TOK + n]], 1);
  __syncthreads();
  int myc = cnt[t];
  int v = myc;
#pragma unroll
  for (int off = 1; off < 64; off <<= 1) {
    int u = __shfl_up(v, off, 64);
    if (lane >= off) v += u;
  }
  if (lane == 63) wsum[w] = v;
  __syncthreads();
  if (t < 9) {
    int s = 0;
    for (int i = 0; i < t; ++i) s += wsum[i];
    wpre[t] = s;
  }
  __syncthreads();
  int inc = v + wpre[w];   // inclusive scan over all 576
  scan[t] = inc;
  offs_g[b0 * C_PAD + t] = inc - myc;
  counts_f[b0 * C_PAD + t] = (t < C_REAL) ? (float)myc : 0.0f;
  wts[b0 * C_PAD + t] = (t < C_REAL && myc > 0) ? 1.0f / (float)myc : 0.0f;
  __syncthreads();
  for (int n = t; n < N_TOK; n += 576) {
    int c = clusters[b0 * N_TOK + n];
    int pos = scan[c] - cnt[c] + atomicAdd(&rank[c], 1);
    sorted[b0 * N_TOK + pos] = n;
  }
}

// ------- kernel 2: unified sorted-gather segmented sums, grid.z = tensor -----
// Per-kernel HBM traffic (round 16 counters): ~225MB in ~36us = ~6.2 TB/s =
// 98% of achievable — the gather IS at the HBM roofline (the "wall" of rounds
// 2-9 was fetch amplification of random 512B rows, not issue logic). Merging
// the three per-tensor kernels into one dispatch removes two kernel-boundary
// tail-drains; z selects tensor (0:q 1:k weighted row-major; 2:v raw,
// transposed via LDS). Branch is block-uniform.
__global__ __launch_bounds__(256) void k_seg3(const float* __restrict__ q,
                                              const float* __restrict__ k,
                                              const float* __restrict__ v,
                                              const int* __restrict__ sorted,
                                              const int* __restrict__ offs_g,
                                              const float* __restrict__ wts,
                                              __hip_bfloat16* __restrict__ q_cb,
                                              __hip_bfloat16* __restrict__ k_cb,
                                              __hip_bfloat16* __restrict__ v_ct) {
  __shared__ float vbuf[CPB][D_DIM];  // 2 KB (v path only)
  int b = blockIdx.x;
  int b0 = b & (NB0 - 1);
  int c0 = blockIdx.y * CPB;
  int tensor = blockIdx.z;
  int wave = threadIdx.x >> 6;
  int lane = threadIdx.x & 63;
  int c = c0 + wave;

  const float* src = (tensor == 0) ? q : (tensor == 1) ? k : v;
  const float* sb = src + (size_t)b * N_TOK * D_DIM;
  const int* sidx = sorted + (size_t)b0 * N_TOK;

  float2 s2 = {0.f, 0.f};
  if (c < C_REAL) {
    int start = offs_g[b0 * C_PAD + c];
    int count = offs_g[b0 * C_PAD + c + 1] - start;
    int l8 = lane & 7;
    int tn = sidx[start + ((l8 < count) ? l8 : 0)];
    float2 xv[8];
#pragma unroll
    for (int j = 0; j < 8; ++j) {
      int n = __shfl(tn, j, 64);
      xv[j] = ((const float2*)(sb + (size_t)n * D_DIM))[lane];
    }
#pragma unroll
    for (int j = 0; j < 8; ++j) {
      bool val = (j < count);   // static index j; mask via cndmask only
      s2.x += val ? xv[j].x : 0.f;
      s2.y += val ? xv[j].y : 0.f;
    }
    if (tensor < 2) {
      float w = wts[b0 * C_PAD + c];
      s2.x *= w; s2.y *= w;
    }
  }

  if (tensor < 2) {
    __hip_bfloat16* dst = (tensor == 0) ? q_cb : k_cb;
    __hip_bfloat162 o;
    o.x = __float2bfloat16(s2.x);
    o.y = __float2bfloat16(s2.y);
    *reinterpret_cast<__hip_bfloat162*>(dst + ((size_t)b * C_PAD + c) * D_DIM + lane * 2) = o;
  } else {
    ((float2*)&vbuf[wave][0])[lane] = s2;
    __syncthreads();
    // transpose-write V: thread t -> dim d = t>>1, 2 clusters per half
    int d = threadIdx.x >> 1;
    int half = threadIdx.x & 1;
    u16x2 o;
#pragma unroll
    for (int j = 0; j < 2; ++j) o[j] = bf16_bits(vbuf[half * 2 + j][d]);
    *reinterpret_cast<u16x2*>(v_ct + ((size_t)b * D_DIM + d) * C_PAD + c0 + half * 2) = o;
  }
}

// ------ kernel 3: cluster attention + fused token broadcast ------------------
// Single-buffer K/V in unified 43KB smem -> 3 blocks/CU (round 16: 65->52us).
// Per-tile {barrier, stage via global_load_lds, vmcnt(0), barrier, compute};
// XOR-swizzled LDS (pre-swizzled global source, rule #21). Broadcast epilogue
// reuses smem as a 64x128 f32 rowbuf; each row written to its <=8 token
// positions as full-wave 512B coalesced stores.
__global__ __launch_bounds__(256) void k_attn(const __hip_bfloat16* __restrict__ q_cb,
                                              const __hip_bfloat16* __restrict__ k_cb,
                                              const __hip_bfloat16* __restrict__ v_ct,
                                              const float* __restrict__ counts_f,
                                              const int* __restrict__ sorted,
                                              const int* __restrict__ offs_g,
                                              float* __restrict__ out,
                                              float* __restrict__ a0_out) {
  __shared__ __align__(16) char smem[44032];  // 43 KB -> 3 blocks/CU
  __hip_bfloat16 (*Kbuf)[D_DIM] = (__hip_bfloat16(*)[D_DIM])smem;          // [64][128]
  __hip_bfloat16 (*Vbuf)[64] = (__hip_bfloat16(*)[64])(smem + 16384);      // [128][64]
  __hip_bfloat16 (*plds)[16][88] = (__hip_bfloat16(*)[16][88])(smem + 32768);
  float* rowbuf = (float*)smem;               // overlays K+V after last tile

  int b = blockIdx.x;
  int b0 = b & (NB0 - 1);
  int tile = blockIdx.y;
  int wave = threadIdx.x >> 6;
  int lane = threadIdx.x & 63;
  int l15 = lane & 15;
  int lhi = lane >> 4;
  int r0 = tile * 64 + wave * 16;

  const __hip_bfloat16* qb = q_cb + (size_t)b * C_PAD * D_DIM;
  const __hip_bfloat16* kb = k_cb + (size_t)b * C_PAD * D_DIM;
  const __hip_bfloat16* vb = v_ct + (size_t)b * D_DIM * C_PAD;
  const float* cnt = counts_f + (size_t)b0 * C_PAD;

  bf16x8 afrag[4];
#pragma unroll
  for (int ks = 0; ks < 4; ++ks)
    afrag[ks] = *(const bf16x8*)(qb + (size_t)(r0 + l15) * D_DIM + ks * 32 + lhi * 8);

  float lsum[4] = {0.f, 0.f, 0.f, 0.f};
  float a0v[4] = {0.f, 0.f, 0.f, 0.f};
  f32x4 oacc[8];
#pragma unroll
  for (int d = 0; d < 8; ++d) oacc[d] = f32x4{0.f, 0.f, 0.f, 0.f};

#define STAGE_KV(jt)                                                           \
  {                                                                            \
    _Pragma("unroll") for (int ii = 0; ii < 4; ++ii) {                         \
      int i = wave * 4 + ii;                                                   \
      int r = i * 4 + (lane >> 4);                                             \
      int cs = (lane & 15) ^ (r & 7);                                          \
      __builtin_amdgcn_global_load_lds(                                        \
          (const void*)(kb + (size_t)((jt) * 64 + r) * D_DIM + cs * 8),        \
          (void*)&Kbuf[i * 4][0], 16, 0, 0);                                   \
    }                                                                          \
    _Pragma("unroll") for (int ii = 0; ii < 4; ++ii) {                         \
      int i = wave * 4 + ii;                                                   \
      int r = i * 8 + (lane >> 3);                                             \
      int cs = (lane & 7) ^ (r & 7);                                           \
      __builtin_amdgcn_global_load_lds(                                        \
          (const void*)(vb + (size_t)r * C_PAD + (jt) * 64 + cs * 8),          \
          (void*)&Vbuf[i * 8][0], 16, 0, 0);                                   \
    }                                                                          \
  }

  for (int jt = 0; jt < NTILE; ++jt) {
    __syncthreads();                                  // all waves done reading
    STAGE_KV(jt);
    asm volatile("s_waitcnt vmcnt(0)" ::: "memory");  // my loads landed
    __syncthreads();                                  // everyone's landed

    f32x4 s[4];
#pragma unroll
    for (int js = 0; js < 4; ++js) {
      s[js] = f32x4{0.f, 0.f, 0.f, 0.f};
#pragma unroll
      for (int ks = 0; ks < 4; ++ks) {
        int slot = (ks * 4 + lhi) ^ (l15 & 7);
        bf16x8 bfrag = *(const bf16x8*)&Kbuf[js * 16 + l15][slot * 8];
        s[js] = __builtin_amdgcn_mfma_f32_16x16x32_bf16(afrag[ks], bfrag, s[js], 0, 0, 0);
      }
    }
    float csub[4];
#pragma unroll
    for (int js = 0; js < 4; ++js) csub[js] = cnt[jt * 64 + js * 16 + l15];

    float ps[4][4];
#pragma unroll
    for (int r = 0; r < 4; ++r) {
#pragma unroll
      for (int js = 0; js < 4; ++js) {
        float p = __expf(s[js][r]);
        ps[js][r] = p;
        lsum[r] += p * csub[js];   // per-lane partial; reduced once at end
      }
    }
    if (jt == 0 && l15 == 0) {
#pragma unroll
      for (int r = 0; r < 4; ++r) a0v[r] = ps[0][r] * csub[0];
    }
#pragma unroll
    for (int js = 0; js < 4; ++js)
#pragma unroll
      for (int r = 0; r < 4; ++r)
        plds[wave][lhi * 4 + r][js * 16 + l15] = __float2bfloat16(ps[js][r]);
    bf16x8 pfrag[2];
#pragma unroll
    for (int k2 = 0; k2 < 2; ++k2)
      pfrag[k2] = *(const bf16x8*)&plds[wave][l15][k2 * 32 + lhi * 8];
#pragma unroll
    for (int d2 = 0; d2 < 8; ++d2) {
      f32x4 o = oacc[d2];
#pragma unroll
      for (int k2 = 0; k2 < 2; ++k2) {
        int slot = (k2 * 4 + lhi) ^ (l15 & 7);
        bf16x8 vfrag = *(const bf16x8*)&Vbuf[d2 * 16 + l15][slot * 8];
        o = __builtin_amdgcn_mfma_f32_16x16x32_bf16(pfrag[k2], vfrag, o, 0, 0, 0);
      }
      oacc[d2] = o;
    }
  }

  // row-sum reduction (rows live across the 16 lanes sharing lhi)
#pragma unroll
  for (int off = 1; off < 16; off <<= 1) {
#pragma unroll
    for (int r = 0; r < 4; ++r) lsum[r] += __shfl_xor(lsum[r], off, 64);
  }
  float inv[4];
#pragma unroll
  for (int r = 0; r < 4; ++r) inv[r] = 1.f / lsum[r];

  // a0 output
#pragma unroll
  for (int r = 0; r < 4; ++r) {
    int row = r0 + lhi * 4 + r;
    if (row < C_REAL && l15 == 0)
      a0_out[(size_t)b * C_REAL + row] = a0v[r] * inv[r];
  }

  // --- fused broadcast: stage 64 output rows in LDS (overlay K+V), then write
  // each row to its <=8 token positions as full-wave 512B stores ---
  __syncthreads();                          // K/V no longer needed
#pragma unroll
  for (int d2 = 0; d2 < 8; ++d2)
#pragma unroll
    for (int r = 0; r < 4; ++r)
      rowbuf[(wave * 16 + lhi * 4 + r) * D_DIM + d2 * 16 + l15] = oacc[d2][r] * inv[r];
  __syncthreads();

  const int* offs = offs_g + b0 * C_PAD;
  const int* sidx = sorted + (size_t)b0 * N_TOK;
  float* outb = out + (size_t)b * N_TOK * D_DIM;
  for (int rr = 0; rr < 16; ++rr) {
    int c = tile * 64 + wave * 16 + rr;
    if (c >= C_REAL) break;                 // wave-uniform
    int start = offs[c];
    int count = offs[c + 1] - start;
    int l8 = lane & 7;
    int tn = sidx[start + ((l8 < count) ? l8 : 0)];
    float2 val = ((const float2*)(rowbuf + (wave * 16 + rr) * D_DIM))[lane];
#pragma unroll
    for (int j = 0; j < 8; ++j) {
      if (j < count) {                      // wave-uniform
        int n = __shfl(tn, j, 64);
        ((float2*)(outb + (size_t)n * D_DIM))[lane] = val;
      }
    }
  }
}

extern "C" void kernel_launch(void* const* d_in, const int* in_sizes, int n_in,
                              void* d_out, int out_size, void* d_ws, size_t ws_size,
                              hipStream_t stream) {
  const float* q = (const float*)d_in[0];
  const float* k = (const float*)d_in[1];
  const float* v = (const float*)d_in[2];
  const int* clusters = (const int*)d_in[3];
  float* out = (float*)d_out;
  float* a0 = out + (size_t)B_TOT * N_TOK * D_DIM;

  char* ws = (char*)d_ws;
  float* counts_f = (float*)ws;
  float* wts = counts_f + NB0 * C_PAD;
  int* offs_g = (int*)(wts + NB0 * C_PAD);
  int* sorted = offs_g + NB0 * C_PAD;
  __hip_bfloat16* q_cb = (__hip_bfloat16*)(sorted + NB0 * N_TOK);
  size_t cbElems = (size_t)B_TOT * C_PAD * D_DIM;
  __hip_bfloat16* k_cb = q_cb + cbElems;
  __hip_bfloat16* v_ct = k_cb + cbElems;

  k_setup<<<NB0, 576, 0, stream>>>(clusters, counts_f, wts, offs_g, sorted);

  k_seg3<<<dim3(B_TOT, C_PAD / CPB, 3), 256, 0, stream>>>(q, k, v, sorted, offs_g,
                                                          wts, q_cb, k_cb, v_ct);

  k_attn<<<dim3(B_TOT, NTILE), 256, 0, stream>>>(q_cb, k_cb, v_ct, counts_f,
                                                 sorted, offs_g, out, a0);
}

// Round 18
// 142.818 us; speedup vs baseline: 1.7459x; 1.1412x over previous
//
#include <hip/hip_runtime.h>
#include <hip/hip_bf16.h>

#define B_TOT 64
#define NB0 8
#define N_TOK 4096
#define D_DIM 128
#define C_REAL 513
#define C_PAD 576
#define NTILE 9   // C_PAD / 64
#define CPB 4     // clusters per segsum block (1 per wave, 4 waves of 256)

typedef __bf16 bf16x8 __attribute__((ext_vector_type(8)));
typedef float f32x4 __attribute__((ext_vector_type(4)));
typedef float f32x2 __attribute__((ext_vector_type(2)));
typedef unsigned short u16x2 __attribute__((ext_vector_type(2)));

static __device__ __forceinline__ unsigned short bf16_bits(float x) {
  __hip_bfloat16 h = __float2bfloat16(x);
  return *reinterpret_cast<unsigned short*>(&h);
}

// ------ kernel 1: per-b0 bincount, weights, shuffle-scan, counting-sort ------
__global__ __launch_bounds__(576) void k_setup(const int* __restrict__ clusters,
                                               float* __restrict__ counts_f,
                                               float* __restrict__ wts,
                                               int* __restrict__ offs_g,
                                               int* __restrict__ sorted) {
  __shared__ int cnt[C_PAD];
  __shared__ int scan[C_PAD];
  __shared__ int rank[C_PAD];
  __shared__ int wsum[9], wpre[9];
  int b0 = blockIdx.x;
  int t = threadIdx.x;
  int lane = t & 63;
  int w = t >> 6;  // 0..8
  cnt[t] = 0;
  rank[t] = 0;
  __syncthreads();
  for (int n = t; n < N_TOK; n += 576)
    atomicAdd(&cnt[clusters[b0 * N_TOK + n]], 1);
  __syncthreads();
  int myc = cnt[t];
  int v = myc;
#pragma unroll
  for (int off = 1; off < 64; off <<= 1) {
    int u = __shfl_up(v, off, 64);
    if (lane >= off) v += u;
  }
  if (lane == 63) wsum[w] = v;
  __syncthreads();
  if (t < 9) {
    int s = 0;
    for (int i = 0; i < t; ++i) s += wsum[i];
    wpre[t] = s;
  }
  __syncthreads();
  int inc = v + wpre[w];   // inclusive scan over all 576
  scan[t] = inc;
  offs_g[b0 * C_PAD + t] = inc - myc;
  counts_f[b0 * C_PAD + t] = (t < C_REAL) ? (float)myc : 0.0f;
  wts[b0 * C_PAD + t] = (t < C_REAL && myc > 0) ? 1.0f / (float)myc : 0.0f;
  __syncthreads();
  for (int n = t; n < N_TOK; n += 576) {
    int c = clusters[b0 * N_TOK + n];
    int pos = scan[c] - cnt[c] + atomicAdd(&rank[c], 1);
    sorted[b0 * N_TOK + pos] = n;
  }
}

// ------- kernel 2: unified sorted-gather segmented sums, grid.z = tensor -----
// Round-17 profile: 135us, FETCH 197MB (demand 402MB, L3 serves 51%), occ 80%
// — latency x MSHR-concurrency capped, NOT bandwidth (HBM-side 1.5 TB/s).
// Lever: average miss latency. Gather loads are read-once -> nontemporal
// (no L1/L2 allocate); with the broadcast's nt stores (below) L3 keeps more
// of q/k/v, shifting misses from ~800ns HBM to ~350ns L3.
__global__ __launch_bounds__(256) void k_seg3(const float* __restrict__ q,
                                              const float* __restrict__ k,
                                              const float* __restrict__ v,
                                              const int* __restrict__ sorted,
                                              const int* __restrict__ offs_g,
                                              const float* __restrict__ wts,
                                              __hip_bfloat16* __restrict__ q_cb,
                                              __hip_bfloat16* __restrict__ k_cb,
                                              __hip_bfloat16* __restrict__ v_ct) {
  __shared__ float vbuf[CPB][D_DIM];  // 2 KB (v path only)
  int b = blockIdx.x;
  int b0 = b & (NB0 - 1);
  int c0 = blockIdx.y * CPB;
  int tensor = blockIdx.z;
  int wave = threadIdx.x >> 6;
  int lane = threadIdx.x & 63;
  int c = c0 + wave;

  const float* src = (tensor == 0) ? q : (tensor == 1) ? k : v;
  const float* sb = src + (size_t)b * N_TOK * D_DIM;
  const int* sidx = sorted + (size_t)b0 * N_TOK;

  f32x2 s2 = {0.f, 0.f};
  if (c < C_REAL) {
    int start = offs_g[b0 * C_PAD + c];
    int count = offs_g[b0 * C_PAD + c + 1] - start;
    int l8 = lane & 7;
    int tn = sidx[start + ((l8 < count) ? l8 : 0)];
    f32x2 xv[8];
#pragma unroll
    for (int j = 0; j < 8; ++j) {
      int n = __shfl(tn, j, 64);
      xv[j] = __builtin_nontemporal_load((const f32x2*)(sb + (size_t)n * D_DIM) + lane);
    }
#pragma unroll
    for (int j = 0; j < 8; ++j) {
      bool val = (j < count);   // static index j; mask via cndmask only
      s2.x += val ? xv[j].x : 0.f;
      s2.y += val ? xv[j].y : 0.f;
    }
    if (tensor < 2) {
      float w = wts[b0 * C_PAD + c];
      s2.x *= w; s2.y *= w;
    }
  }

  if (tensor < 2) {
    __hip_bfloat16* dst = (tensor == 0) ? q_cb : k_cb;
    __hip_bfloat162 o;
    o.x = __float2bfloat16(s2.x);
    o.y = __float2bfloat16(s2.y);
    *reinterpret_cast<__hip_bfloat162*>(dst + ((size_t)b * C_PAD + c) * D_DIM + lane * 2) = o;
  } else {
    ((f32x2*)&vbuf[wave][0])[lane] = s2;
    __syncthreads();
    // transpose-write V: thread t -> dim d = t>>1, 2 clusters per half
    int d = threadIdx.x >> 1;
    int half = threadIdx.x & 1;
    u16x2 o;
#pragma unroll
    for (int j = 0; j < 2; ++j) o[j] = bf16_bits(vbuf[half * 2 + j][d]);
    *reinterpret_cast<u16x2*>(v_ct + ((size_t)b * D_DIM + d) * C_PAD + c0 + half * 2) = o;
  }
}

// ------ kernel 3: cluster attention + fused token broadcast ------------------
// Single-buffer K/V in unified 43KB smem -> 3 blocks/CU. Broadcast stores are
// NONTEMPORAL: out (134MB/iter) must not evict q/k/v from L3 (seg's latency
// depends on L3 hit rate).
__global__ __launch_bounds__(256) void k_attn(const __hip_bfloat16* __restrict__ q_cb,
                                              const __hip_bfloat16* __restrict__ k_cb,
                                              const __hip_bfloat16* __restrict__ v_ct,
                                              const float* __restrict__ counts_f,
                                              const int* __restrict__ sorted,
                                              const int* __restrict__ offs_g,
                                              float* __restrict__ out,
                                              float* __restrict__ a0_out) {
  __shared__ __align__(16) char smem[44032];  // 43 KB -> 3 blocks/CU
  __hip_bfloat16 (*Kbuf)[D_DIM] = (__hip_bfloat16(*)[D_DIM])smem;          // [64][128]
  __hip_bfloat16 (*Vbuf)[64] = (__hip_bfloat16(*)[64])(smem + 16384);      // [128][64]
  __hip_bfloat16 (*plds)[16][88] = (__hip_bfloat16(*)[16][88])(smem + 32768);
  float* rowbuf = (float*)smem;               // overlays K+V after last tile

  int b = blockIdx.x;
  int b0 = b & (NB0 - 1);
  int tile = blockIdx.y;
  int wave = threadIdx.x >> 6;
  int lane = threadIdx.x & 63;
  int l15 = lane & 15;
  int lhi = lane >> 4;
  int r0 = tile * 64 + wave * 16;

  const __hip_bfloat16* qb = q_cb + (size_t)b * C_PAD * D_DIM;
  const __hip_bfloat16* kb = k_cb + (size_t)b * C_PAD * D_DIM;
  const __hip_bfloat16* vb = v_ct + (size_t)b * D_DIM * C_PAD;
  const float* cnt = counts_f + (size_t)b0 * C_PAD;

  bf16x8 afrag[4];
#pragma unroll
  for (int ks = 0; ks < 4; ++ks)
    afrag[ks] = *(const bf16x8*)(qb + (size_t)(r0 + l15) * D_DIM + ks * 32 + lhi * 8);

  float lsum[4] = {0.f, 0.f, 0.f, 0.f};
  float a0v[4] = {0.f, 0.f, 0.f, 0.f};
  f32x4 oacc[8];
#pragma unroll
  for (int d = 0; d < 8; ++d) oacc[d] = f32x4{0.f, 0.f, 0.f, 0.f};

#define STAGE_KV(jt)                                                           \
  {                                                                            \
    _Pragma("unroll") for (int ii = 0; ii < 4; ++ii) {                         \
      int i = wave * 4 + ii;                                                   \
      int r = i * 4 + (lane >> 4);                                             \
      int cs = (lane & 15) ^ (r & 7);                                          \
      __builtin_amdgcn_global_load_lds(                                        \
          (const void*)(kb + (size_t)((jt) * 64 + r) * D_DIM + cs * 8),        \
          (void*)&Kbuf[i * 4][0], 16, 0, 0);                                   \
    }                                                                          \
    _Pragma("unroll") for (int ii = 0; ii < 4; ++ii) {                         \
      int i = wave * 4 + ii;                                                   \
      int r = i * 8 + (lane >> 3);                                             \
      int cs = (lane & 7) ^ (r & 7);                                           \
      __builtin_amdgcn_global_load_lds(                                        \
          (const void*)(vb + (size_t)r * C_PAD + (jt) * 64 + cs * 8),          \
          (void*)&Vbuf[i * 8][0], 16, 0, 0);                                   \
    }                                                                          \
  }

  for (int jt = 0; jt < NTILE; ++jt) {
    __syncthreads();                                  // all waves done reading
    STAGE_KV(jt);
    asm volatile("s_waitcnt vmcnt(0)" ::: "memory");  // my loads landed
    __syncthreads();                                  // everyone's landed

    f32x4 s[4];
#pragma unroll
    for (int js = 0; js < 4; ++js) {
      s[js] = f32x4{0.f, 0.f, 0.f, 0.f};
#pragma unroll
      for (int ks = 0; ks < 4; ++ks) {
        int slot = (ks * 4 + lhi) ^ (l15 & 7);
        bf16x8 bfrag = *(const bf16x8*)&Kbuf[js * 16 + l15][slot * 8];
        s[js] = __builtin_amdgcn_mfma_f32_16x16x32_bf16(afrag[ks], bfrag, s[js], 0, 0, 0);
      }
    }
    float csub[4];
#pragma unroll
    for (int js = 0; js < 4; ++js) csub[js] = cnt[jt * 64 + js * 16 + l15];

    float ps[4][4];
#pragma unroll
    for (int r = 0; r < 4; ++r) {
#pragma unroll
      for (int js = 0; js < 4; ++js) {
        float p = __expf(s[js][r]);
        ps[js][r] = p;
        lsum[r] += p * csub[js];   // per-lane partial; reduced once at end
      }
    }
    if (jt == 0 && l15 == 0) {
#pragma unroll
      for (int r = 0; r < 4; ++r) a0v[r] = ps[0][r] * csub[0];
    }
#pragma unroll
    for (int js = 0; js < 4; ++js)
#pragma unroll
      for (int r = 0; r < 4; ++r)
        plds[wave][lhi * 4 + r][js * 16 + l15] = __float2bfloat16(ps[js][r]);
    bf16x8 pfrag[2];
#pragma unroll
    for (int k2 = 0; k2 < 2; ++k2)
      pfrag[k2] = *(const bf16x8*)&plds[wave][l15][k2 * 32 + lhi * 8];
#pragma unroll
    for (int d2 = 0; d2 < 8; ++d2) {
      f32x4 o = oacc[d2];
#pragma unroll
      for (int k2 = 0; k2 < 2; ++k2) {
        int slot = (k2 * 4 + lhi) ^ (l15 & 7);
        bf16x8 vfrag = *(const bf16x8*)&Vbuf[d2 * 16 + l15][slot * 8];
        o = __builtin_amdgcn_mfma_f32_16x16x32_bf16(pfrag[k2], vfrag, o, 0, 0, 0);
      }
      oacc[d2] = o;
    }
  }

  // row-sum reduction (rows live across the 16 lanes sharing lhi)
#pragma unroll
  for (int off = 1; off < 16; off <<= 1) {
#pragma unroll
    for (int r = 0; r < 4; ++r) lsum[r] += __shfl_xor(lsum[r], off, 64);
  }
  float inv[4];
#pragma unroll
  for (int r = 0; r < 4; ++r) inv[r] = 1.f / lsum[r];

  // a0 output
#pragma unroll
  for (int r = 0; r < 4; ++r) {
    int row = r0 + lhi * 4 + r;
    if (row < C_REAL && l15 == 0)
      a0_out[(size_t)b * C_REAL + row] = a0v[r] * inv[r];
  }

  // --- fused broadcast: stage 64 output rows in LDS (overlay K+V), then write
  // each row to its <=8 token positions as full-wave 512B NT stores ---
  __syncthreads();                          // K/V no longer needed
#pragma unroll
  for (int d2 = 0; d2 < 8; ++d2)
#pragma unroll
    for (int r = 0; r < 4; ++r)
      rowbuf[(wave * 16 + lhi * 4 + r) * D_DIM + d2 * 16 + l15] = oacc[d2][r] * inv[r];
  __syncthreads();

  const int* offs = offs_g + b0 * C_PAD;
  const int* sidx = sorted + (size_t)b0 * N_TOK;
  float* outb = out + (size_t)b * N_TOK * D_DIM;
  for (int rr = 0; rr < 16; ++rr) {
    int c = tile * 64 + wave * 16 + rr;
    if (c >= C_REAL) break;                 // wave-uniform
    int start = offs[c];
    int count = offs[c + 1] - start;
    int l8 = lane & 7;
    int tn = sidx[start + ((l8 < count) ? l8 : 0)];
    f32x2 val = ((const f32x2*)(rowbuf + (wave * 16 + rr) * D_DIM))[lane];
#pragma unroll
    for (int j = 0; j < 8; ++j) {
      if (j < count) {                      // wave-uniform
        int n = __shfl(tn, j, 64);
        __builtin_nontemporal_store(val, (f32x2*)(outb + (size_t)n * D_DIM) + lane);
      }
    }
  }
}

extern "C" void kernel_launch(void* const* d_in, const int* in_sizes, int n_in,
                              void* d_out, int out_size, void* d_ws, size_t ws_size,
                              hipStream_t stream) {
  const float* q = (const float*)d_in[0];
  const float* k = (const float*)d_in[1];
  const float* v = (const float*)d_in[2];
  const int* clusters = (const int*)d_in[3];
  float* out = (float*)d_out;
  float* a0 = out + (size_t)B_TOT * N_TOK * D_DIM;

  char* ws = (char*)d_ws;
  float* counts_f = (float*)ws;
  float* wts = counts_f + NB0 * C_PAD;
  int* offs_g = (int*)(wts + NB0 * C_PAD);
  int* sorted = offs_g + NB0 * C_PAD;
  __hip_bfloat16* q_cb = (__hip_bfloat16*)(sorted + NB0 * N_TOK);
  size_t cbElems = (size_t)B_TOT * C_PAD * D_DIM;
  __hip_bfloat16* k_cb = q_cb + cbElems;
  __hip_bfloat16* v_ct = k_cb + cbElems;

  k_setup<<<NB0, 576, 0, stream>>>(clusters, counts_f, wts, offs_g, sorted);

  k_seg3<<<dim3(B_TOT, C_PAD / CPB, 3), 256, 0, stream>>>(q, k, v, sorted, offs_g,
                                                          wts, q_cb, k_cb, v_ct);

  k_attn<<<dim3(B_TOT, NTILE), 256, 0, stream>>>(q_cb, k_cb, v_ct, counts_f,
                                                 sorted, offs_g, out, a0);
}

// Round 19
// 140.440 us; speedup vs baseline: 1.7754x; 1.0169x over previous
//
#include <hip/hip_runtime.h>
#include <hip/hip_bf16.h>

#define B_TOT 64
#define NB0 8
#define N_TOK 4096
#define D_DIM 128
#define C_REAL 513
#define C_PAD 576
#define NTILE 9   // C_PAD / 64
#define CPB 4     // clusters per segsum block (1 per wave, 4 waves of 256)

typedef __bf16 bf16x8 __attribute__((ext_vector_type(8)));
typedef float f32x4 __attribute__((ext_vector_type(4)));
typedef float f32x2 __attribute__((ext_vector_type(2)));
typedef unsigned short u16x2 __attribute__((ext_vector_type(2)));
typedef unsigned short u16x4 __attribute__((ext_vector_type(4)));

static __device__ __forceinline__ unsigned short bf16_bits(float x) {
  __hip_bfloat16 h = __float2bfloat16(x);
  return *reinterpret_cast<unsigned short*>(&h);
}

// ------ kernel 1: per-b0 bincount, weights, shuffle-scan, counting-sort ------
__global__ __launch_bounds__(576) void k_setup(const int* __restrict__ clusters,
                                               float* __restrict__ counts_f,
                                               float* __restrict__ wts,
                                               int* __restrict__ offs_g,
                                               int* __restrict__ sorted) {
  __shared__ int cnt[C_PAD];
  __shared__ int scan[C_PAD];
  __shared__ int rank[C_PAD];
  __shared__ int wsum[9], wpre[9];
  int b0 = blockIdx.x;
  int t = threadIdx.x;
  int lane = t & 63;
  int w = t >> 6;  // 0..8
  cnt[t] = 0;
  rank[t] = 0;
  __syncthreads();
  for (int n = t; n < N_TOK; n += 576)
    atomicAdd(&cnt[clusters[b0 * N_TOK + n]], 1);
  __syncthreads();
  int myc = cnt[t];
  int v = myc;
#pragma unroll
  for (int off = 1; off < 64; off <<= 1) {
    int u = __shfl_up(v, off, 64);
    if (lane >= off) v += u;
  }
  if (lane == 63) wsum[w] = v;
  __syncthreads();
  if (t < 9) {
    int s = 0;
    for (int i = 0; i < t; ++i) s += wsum[i];
    wpre[t] = s;
  }
  __syncthreads();
  int inc = v + wpre[w];   // inclusive scan over all 576
  scan[t] = inc;
  offs_g[b0 * C_PAD + t] = inc - myc;
  counts_f[b0 * C_PAD + t] = (t < C_REAL) ? (float)myc : 0.0f;
  wts[b0 * C_PAD + t] = (t < C_REAL && myc > 0) ? 1.0f / (float)myc : 0.0f;
  __syncthreads();
  for (int n = t; n < N_TOK; n += 576) {
    int c = clusters[b0 * N_TOK + n];
    int pos = scan[c] - cnt[c] + atomicAdd(&rank[c], 1);
    sorted[b0 * N_TOK + pos] = n;
  }
}

// ------- kernel 2: unified sorted-gather segmented sums, grid.z = tensor -----
// Round-18: nt loads cut 135->88us (demand 4.6 TB/s; mandatory-byte floor
// 64us). Remaining gap is issue overhead: switch to 2-rows-per-load dwordx4
// (lanes 0-31 row 2j, lanes 32-63 row 2j+1; 1KB/instr) -> 4 loads + 4 masked
// adds per cluster instead of 8+8, one shfl_xor(32) merges even/odd partials.
__global__ __launch_bounds__(256) void k_seg3(const float* __restrict__ q,
                                              const float* __restrict__ k,
                                              const float* __restrict__ v,
                                              const int* __restrict__ sorted,
                                              const int* __restrict__ offs_g,
                                              const float* __restrict__ wts,
                                              __hip_bfloat16* __restrict__ q_cb,
                                              __hip_bfloat16* __restrict__ k_cb,
                                              __hip_bfloat16* __restrict__ v_ct) {
  __shared__ float vbuf[CPB][D_DIM];  // 2 KB (v path only)
  int b = blockIdx.x;
  int b0 = b & (NB0 - 1);
  int c0 = blockIdx.y * CPB;
  int tensor = blockIdx.z;
  int wave = threadIdx.x >> 6;
  int lane = threadIdx.x & 63;
  int c = c0 + wave;
  int l16 = lane & 31;      // lane within half-wave
  int hi = lane >> 5;       // 0: even rows, 1: odd rows

  const float* src = (tensor == 0) ? q : (tensor == 1) ? k : v;
  const float* sb = src + (size_t)b * N_TOK * D_DIM;
  const int* sidx = sorted + (size_t)b0 * N_TOK;

  f32x4 s4 = {0.f, 0.f, 0.f, 0.f};
  if (c < C_REAL) {
    int start = offs_g[b0 * C_PAD + c];
    int count = offs_g[b0 * C_PAD + c + 1] - start;
    int l8 = lane & 7;
    int tn = sidx[start + ((l8 < count) ? l8 : 0)];

    f32x4 xv[4];
#pragma unroll
    for (int j = 0; j < 4; ++j) {
      int n = __shfl(tn, 2 * j + hi, 64);
      xv[j] = __builtin_nontemporal_load((const f32x4*)(sb + (size_t)n * D_DIM) + l16);
    }
#pragma unroll
    for (int j = 0; j < 4; ++j) {
      bool val = (2 * j + hi) < count;  // static index j; mask via cndmask
      s4 += val ? xv[j] : f32x4{0.f, 0.f, 0.f, 0.f};
    }
    // merge even-row (lanes 0-31) and odd-row (lanes 32-63) partials
    f32x4 o;
    o.x = __shfl_xor(s4.x, 32, 64);
    o.y = __shfl_xor(s4.y, 32, 64);
    o.z = __shfl_xor(s4.z, 32, 64);
    o.w = __shfl_xor(s4.w, 32, 64);
    s4 += o;
    if (tensor < 2) {
      float w = wts[b0 * C_PAD + c];
      s4 *= w;
    }
  }

  if (tensor < 2) {
    if (hi == 0) {  // lanes 0-31 hold full sums for dims l16*4..+3
      __hip_bfloat16* dst = (tensor == 0) ? q_cb : k_cb;
      u16x4 o;
      o[0] = bf16_bits(s4.x);
      o[1] = bf16_bits(s4.y);
      o[2] = bf16_bits(s4.z);
      o[3] = bf16_bits(s4.w);
      *reinterpret_cast<u16x4*>(dst + ((size_t)b * C_PAD + c) * D_DIM + l16 * 4) = o;
    }
  } else {
    if (hi == 0) ((f32x4*)&vbuf[wave][0])[l16] = s4;
    __syncthreads();
    // transpose-write V: thread t -> dim d = t>>1, 2 clusters per half
    int d = threadIdx.x >> 1;
    int half = threadIdx.x & 1;
    u16x2 o;
#pragma unroll
    for (int j = 0; j < 2; ++j) o[j] = bf16_bits(vbuf[half * 2 + j][d]);
    *reinterpret_cast<u16x2*>(v_ct + ((size_t)b * D_DIM + d) * C_PAD + c0 + half * 2) = o;
  }
}

// ------ kernel 3: cluster attention + fused token broadcast ------------------
// Single-buffer K/V in unified 43KB smem -> 3 blocks/CU. Broadcast stores are
// NONTEMPORAL: out (134MB/iter) must not evict q/k/v from L3 (seg's latency
// depends on L3 hit rate; round-18: nt was worth 20us total).
__global__ __launch_bounds__(256) void k_attn(const __hip_bfloat16* __restrict__ q_cb,
                                              const __hip_bfloat16* __restrict__ k_cb,
                                              const __hip_bfloat16* __restrict__ v_ct,
                                              const float* __restrict__ counts_f,
                                              const int* __restrict__ sorted,
                                              const int* __restrict__ offs_g,
                                              float* __restrict__ out,
                                              float* __restrict__ a0_out) {
  __shared__ __align__(16) char smem[44032];  // 43 KB -> 3 blocks/CU
  __hip_bfloat16 (*Kbuf)[D_DIM] = (__hip_bfloat16(*)[D_DIM])smem;          // [64][128]
  __hip_bfloat16 (*Vbuf)[64] = (__hip_bfloat16(*)[64])(smem + 16384);      // [128][64]
  __hip_bfloat16 (*plds)[16][88] = (__hip_bfloat16(*)[16][88])(smem + 32768);
  float* rowbuf = (float*)smem;               // overlays K+V after last tile

  int b = blockIdx.x;
  int b0 = b & (NB0 - 1);
  int tile = blockIdx.y;
  int wave = threadIdx.x >> 6;
  int lane = threadIdx.x & 63;
  int l15 = lane & 15;
  int lhi = lane >> 4;
  int r0 = tile * 64 + wave * 16;

  const __hip_bfloat16* qb = q_cb + (size_t)b * C_PAD * D_DIM;
  const __hip_bfloat16* kb = k_cb + (size_t)b * C_PAD * D_DIM;
  const __hip_bfloat16* vb = v_ct + (size_t)b * D_DIM * C_PAD;
  const float* cnt = counts_f + (size_t)b0 * C_PAD;

  bf16x8 afrag[4];
#pragma unroll
  for (int ks = 0; ks < 4; ++ks)
    afrag[ks] = *(const bf16x8*)(qb + (size_t)(r0 + l15) * D_DIM + ks * 32 + lhi * 8);

  float lsum[4] = {0.f, 0.f, 0.f, 0.f};
  float a0v[4] = {0.f, 0.f, 0.f, 0.f};
  f32x4 oacc[8];
#pragma unroll
  for (int d = 0; d < 8; ++d) oacc[d] = f32x4{0.f, 0.f, 0.f, 0.f};

#define STAGE_KV(jt)                                                           \
  {                                                                            \
    _Pragma("unroll") for (int ii = 0; ii < 4; ++ii) {                         \
      int i = wave * 4 + ii;                                                   \
      int r = i * 4 + (lane >> 4);                                             \
      int cs = (lane & 15) ^ (r & 7);                                          \
      __builtin_amdgcn_global_load_lds(                                        \
          (const void*)(kb + (size_t)((jt) * 64 + r) * D_DIM + cs * 8),        \
          (void*)&Kbuf[i * 4][0], 16, 0, 0);                                   \
    }                                                                          \
    _Pragma("unroll") for (int ii = 0; ii < 4; ++ii) {                         \
      int i = wave * 4 + ii;                                                   \
      int r = i * 8 + (lane >> 3);                                             \
      int cs = (lane & 7) ^ (r & 7);                                           \
      __builtin_amdgcn_global_load_lds(                                        \
          (const void*)(vb + (size_t)r * C_PAD + (jt) * 64 + cs * 8),          \
          (void*)&Vbuf[i * 8][0], 16, 0, 0);                                   \
    }                                                                          \
  }

  for (int jt = 0; jt < NTILE; ++jt) {
    __syncthreads();                                  // all waves done reading
    STAGE_KV(jt);
    asm volatile("s_waitcnt vmcnt(0)" ::: "memory");  // my loads landed
    __syncthreads();                                  // everyone's landed

    f32x4 s[4];
#pragma unroll
    for (int js = 0; js < 4; ++js) {
      s[js] = f32x4{0.f, 0.f, 0.f, 0.f};
#pragma unroll
      for (int ks = 0; ks < 4; ++ks) {
        int slot = (ks * 4 + lhi) ^ (l15 & 7);
        bf16x8 bfrag = *(const bf16x8*)&Kbuf[js * 16 + l15][slot * 8];
        s[js] = __builtin_amdgcn_mfma_f32_16x16x32_bf16(afrag[ks], bfrag, s[js], 0, 0, 0);
      }
    }
    float csub[4];
#pragma unroll
    for (int js = 0; js < 4; ++js) csub[js] = cnt[jt * 64 + js * 16 + l15];

    float ps[4][4];
#pragma unroll
    for (int r = 0; r < 4; ++r) {
#pragma unroll
      for (int js = 0; js < 4; ++js) {
        float p = __expf(s[js][r]);
        ps[js][r] = p;
        lsum[r] += p * csub[js];   // per-lane partial; reduced once at end
      }
    }
    if (jt == 0 && l15 == 0) {
#pragma unroll
      for (int r = 0; r < 4; ++r) a0v[r] = ps[0][r] * csub[0];
    }
#pragma unroll
    for (int js = 0; js < 4; ++js)
#pragma unroll
      for (int r = 0; r < 4; ++r)
        plds[wave][lhi * 4 + r][js * 16 + l15] = __float2bfloat16(ps[js][r]);
    bf16x8 pfrag[2];
#pragma unroll
    for (int k2 = 0; k2 < 2; ++k2)
      pfrag[k2] = *(const bf16x8*)&plds[wave][l15][k2 * 32 + lhi * 8];
#pragma unroll
    for (int d2 = 0; d2 < 8; ++d2) {
      f32x4 o = oacc[d2];
#pragma unroll
      for (int k2 = 0; k2 < 2; ++k2) {
        int slot = (k2 * 4 + lhi) ^ (l15 & 7);
        bf16x8 vfrag = *(const bf16x8*)&Vbuf[d2 * 16 + l15][slot * 8];
        o = __builtin_amdgcn_mfma_f32_16x16x32_bf16(pfrag[k2], vfrag, o, 0, 0, 0);
      }
      oacc[d2] = o;
    }
  }

  // row-sum reduction (rows live across the 16 lanes sharing lhi)
#pragma unroll
  for (int off = 1; off < 16; off <<= 1) {
#pragma unroll
    for (int r = 0; r < 4; ++r) lsum[r] += __shfl_xor(lsum[r], off, 64);
  }
  float inv[4];
#pragma unroll
  for (int r = 0; r < 4; ++r) inv[r] = 1.f / lsum[r];

  // a0 output
#pragma unroll
  for (int r = 0; r < 4; ++r) {
    int row = r0 + lhi * 4 + r;
    if (row < C_REAL && l15 == 0)
      a0_out[(size_t)b * C_REAL + row] = a0v[r] * inv[r];
  }

  // --- fused broadcast: stage 64 output rows in LDS (overlay K+V), then write
  // each row to its <=8 token positions as full-wave 512B NT stores ---
  __syncthreads();                          // K/V no longer needed
#pragma unroll
  for (int d2 = 0; d2 < 8; ++d2)
#pragma unroll
    for (int r = 0; r < 4; ++r)
      rowbuf[(wave * 16 + lhi * 4 + r) * D_DIM + d2 * 16 + l15] = oacc[d2][r] * inv[r];
  __syncthreads();

  const int* offs = offs_g + b0 * C_PAD;
  const int* sidx = sorted + (size_t)b0 * N_TOK;
  float* outb = out + (size_t)b * N_TOK * D_DIM;
  for (int rr = 0; rr < 16; ++rr) {
    int c = tile * 64 + wave * 16 + rr;
    if (c >= C_REAL) break;                 // wave-uniform
    int start = offs[c];
    int count = offs[c + 1] - start;
    int l8 = lane & 7;
    int tn = sidx[start + ((l8 < count) ? l8 : 0)];
    f32x2 val = ((const f32x2*)(rowbuf + (wave * 16 + rr) * D_DIM))[lane];
#pragma unroll
    for (int j = 0; j < 8; ++j) {
      if (j < count) {                      // wave-uniform
        int n = __shfl(tn, j, 64);
        __builtin_nontemporal_store(val, (f32x2*)(outb + (size_t)n * D_DIM) + lane);
      }
    }
  }
}

extern "C" void kernel_launch(void* const* d_in, const int* in_sizes, int n_in,
                              void* d_out, int out_size, void* d_ws, size_t ws_size,
                              hipStream_t stream) {
  const float* q = (const float*)d_in[0];
  const float* k = (const float*)d_in[1];
  const float* v = (const float*)d_in[2];
  const int* clusters = (const int*)d_in[3];
  float* out = (float*)d_out;
  float* a0 = out + (size_t)B_TOT * N_TOK * D_DIM;

  char* ws = (char*)d_ws;
  float* counts_f = (float*)ws;
  float* wts = counts_f + NB0 * C_PAD;
  int* offs_g = (int*)(wts + NB0 * C_PAD);
  int* sorted = offs_g + NB0 * C_PAD;
  __hip_bfloat16* q_cb = (__hip_bfloat16*)(sorted + NB0 * N_TOK);
  size_t cbElems = (size_t)B_TOT * C_PAD * D_DIM;
  __hip_bfloat16* k_cb = q_cb + cbElems;
  __hip_bfloat16* v_ct = k_cb + cbElems;

  k_setup<<<NB0, 576, 0, stream>>>(clusters, counts_f, wts, offs_g, sorted);

  k_seg3<<<dim3(B_TOT, C_PAD / CPB, 3), 256, 0, stream>>>(q, k, v, sorted, offs_g,
                                                          wts, q_cb, k_cb, v_ct);

  k_attn<<<dim3(B_TOT, NTILE), 256, 0, stream>>>(q_cb, k_cb, v_ct, counts_f,
                                                 sorted, offs_g, out, a0);
}